// Round 1
// baseline (578.289 us; speedup 1.0000x reference)
//
#include <hip/hip_runtime.h>
#include <math.h>

#define D_MODEL 1024
#define D_STATE 16
#define D_CONV  4
#define D_INNER 2048
#define DT_RANK 64
#define B_SZ    4
#define L_SEQ   2048

// d_out layout (floats): dt | A | B | C | x
#define OFF_DT 0
#define OFF_A  (B_SZ * D_INNER * L_SEQ)
#define OFF_B  (OFF_A + D_INNER * D_STATE)
#define OFF_C  (OFF_B + B_SZ * D_STATE * L_SEQ)
#define OFF_X  (OFF_C + B_SZ * D_STATE * L_SEQ)

// ---------------------------------------------------------------------------
// K1: in_proj (x half only): C[b][d][l] = sum_k W[d][k] * HS[b][l][k]
// NT GEMM, 64x64 tile, BK=16, 256 threads, 4x4 per thread. fp32.
// ---------------------------------------------------------------------------
__global__ __launch_bounds__(256) void k_inproj(const float* __restrict__ W,
                                                const float* __restrict__ HS,
                                                float* __restrict__ Cout) {
  const int b  = blockIdx.z;
  const int bm = blockIdx.y;
  const int bn = blockIdx.x;
  __shared__ float As[16][68];  // k-major, padded; b128-aligned reads
  __shared__ float Bs[16][68];
  const int tid  = threadIdx.x;
  const int lrow = tid >> 2;         // 0..63
  const int lcol = (tid & 3) << 2;   // 0,4,8,12
  const int tx = tid & 15, ty = tid >> 4;

  const float* Ag = W + (size_t)(bm * 64 + lrow) * D_MODEL + lcol;
  const float* Bg = HS + (size_t)b * L_SEQ * D_MODEL
                       + (size_t)(bn * 64 + lrow) * D_MODEL + lcol;
  float acc[4][4] = {};

  for (int k0 = 0; k0 < D_MODEL; k0 += 16) {
    float4 av = *(const float4*)(Ag + k0);
    float4 bv = *(const float4*)(Bg + k0);
    As[lcol + 0][lrow] = av.x; As[lcol + 1][lrow] = av.y;
    As[lcol + 2][lrow] = av.z; As[lcol + 3][lrow] = av.w;
    Bs[lcol + 0][lrow] = bv.x; Bs[lcol + 1][lrow] = bv.y;
    Bs[lcol + 2][lrow] = bv.z; Bs[lcol + 3][lrow] = bv.w;
    __syncthreads();
#pragma unroll
    for (int kk = 0; kk < 16; ++kk) {
      float4 a4 = *(const float4*)&As[kk][ty << 2];
      float4 b4 = *(const float4*)&Bs[kk][tx << 2];
      float a[4] = {a4.x, a4.y, a4.z, a4.w};
      float bb[4] = {b4.x, b4.y, b4.z, b4.w};
#pragma unroll
      for (int i = 0; i < 4; ++i)
#pragma unroll
        for (int j = 0; j < 4; ++j) acc[i][j] += a[i] * bb[j];
    }
    __syncthreads();
  }

  float* Cp = Cout + (size_t)b * D_INNER * L_SEQ
                   + (size_t)(bm * 64 + (ty << 2)) * L_SEQ + bn * 64 + (tx << 2);
#pragma unroll
  for (int i = 0; i < 4; ++i) {
    float4 v = make_float4(acc[i][0], acc[i][1], acc[i][2], acc[i][3]);
    *(float4*)(Cp + (size_t)i * L_SEQ) = v;
  }
}

// ---------------------------------------------------------------------------
// K2: causal depthwise conv4 + bias + SiLU. One block per (b,d) row.
// ---------------------------------------------------------------------------
__global__ __launch_bounds__(512) void k_conv(const float* __restrict__ Xp,
                                              const float* __restrict__ CW,
                                              const float* __restrict__ CB,
                                              float* __restrict__ Xo) {
  const int bd = blockIdx.x;            // b*D_INNER + d
  const int d  = bd & (D_INNER - 1);
  const float* row = Xp + (size_t)bd * L_SEQ;
  float* orow = Xo + (size_t)bd * L_SEQ;
  const float w0 = CW[d * 4 + 0], w1 = CW[d * 4 + 1];
  const float w2 = CW[d * 4 + 2], w3 = CW[d * 4 + 3];
  const float bias = CB[d];
  const int l0 = threadIdx.x << 2;
  float4 cur = *(const float4*)(row + l0);
  float p1 = 0.f, p2 = 0.f, p3 = 0.f;   // row[l0-1], row[l0-2], row[l0-3]
  if (l0 >= 4) {
    float4 prev = *(const float4*)(row + l0 - 4);
    p3 = prev.y; p2 = prev.z; p1 = prev.w;
  }
  float v0 = w0 * p3    + w1 * p2    + w2 * p1    + w3 * cur.x + bias;
  float v1 = w0 * p2    + w1 * p1    + w2 * cur.x + w3 * cur.y + bias;
  float v2 = w0 * p1    + w1 * cur.x + w2 * cur.y + w3 * cur.z + bias;
  float v3 = w0 * cur.x + w1 * cur.y + w2 * cur.z + w3 * cur.w + bias;
  float4 o;
  o.x = v0 / (1.f + expf(-v0));
  o.y = v1 / (1.f + expf(-v1));
  o.z = v2 / (1.f + expf(-v2));
  o.w = v3 / (1.f + expf(-v3));
  *(float4*)(orow + l0) = o;
}

// ---------------------------------------------------------------------------
// K3: x_proj: C[b][e][l] = sum_d XW[e][d] * X[b][d][l]   (NN GEMM)
// M=96 (3 tiles of 32), N-tile=128, BK=32, 256 threads, 4x4 per thread.
// Rows 0..63 -> ws (dt_low); rows 64..79 -> B_mat; rows 80..95 -> C_mat.
// ---------------------------------------------------------------------------
__global__ __launch_bounds__(256) void k_xproj(const float* __restrict__ XW,
                                               const float* __restrict__ X,
                                               float* __restrict__ XDBL,
                                               float* __restrict__ OutB,
                                               float* __restrict__ OutC) {
  const int b  = blockIdx.z;
  const int bm = blockIdx.y;   // 0..2
  const int bn = blockIdx.x;   // 0..15
  __shared__ float As[32][36];   // k-major
  __shared__ float Bs[32][132];  // [k][n], padded (byte stride 528, 16-aligned)
  const int tid = threadIdx.x;
  const int tx = tid & 31, ty = tid >> 5;
  const int arow = tid >> 3;         // 0..31
  const int acol = (tid & 7) << 2;   // 0..28
  const float* Xb = X + (size_t)b * D_INNER * L_SEQ;
  const float* Ag = XW + (size_t)(bm * 32 + arow) * D_INNER + acol;
  float acc[4][4] = {};

  for (int k0 = 0; k0 < D_INNER; k0 += 32) {
    float4 av = *(const float4*)(Ag + k0);
    As[acol + 0][arow] = av.x; As[acol + 1][arow] = av.y;
    As[acol + 2][arow] = av.z; As[acol + 3][arow] = av.w;
#pragma unroll
    for (int q = 0; q < 4; ++q) {
      int brow = q * 8 + (tid >> 5);
      int bcol = (tid & 31) << 2;
      float4 bv = *(const float4*)(Xb + (size_t)(k0 + brow) * L_SEQ + bn * 128 + bcol);
      *(float4*)&Bs[brow][bcol] = bv;
    }
    __syncthreads();
#pragma unroll
    for (int kk = 0; kk < 32; ++kk) {
      float4 a4 = *(const float4*)&As[kk][ty << 2];
      float4 b4 = *(const float4*)&Bs[kk][tx << 2];
      float a[4] = {a4.x, a4.y, a4.z, a4.w};
      float bb[4] = {b4.x, b4.y, b4.z, b4.w};
#pragma unroll
      for (int i = 0; i < 4; ++i)
#pragma unroll
        for (int j = 0; j < 4; ++j) acc[i][j] += a[i] * bb[j];
    }
    __syncthreads();
  }

  const int n0 = bn * 128 + (tx << 2);
#pragma unroll
  for (int i = 0; i < 4; ++i) {
    int e = bm * 32 + (ty << 2) + i;
    float4 v = make_float4(acc[i][0], acc[i][1], acc[i][2], acc[i][3]);
    if (bm < 2) {
      *(float4*)(XDBL + (size_t)b * DT_RANK * L_SEQ + (size_t)e * L_SEQ + n0) = v;
    } else {
      int r = e - DT_RANK;
      if (r < D_STATE)
        *(float4*)(OutB + (size_t)b * D_STATE * L_SEQ + (size_t)r * L_SEQ + n0) = v;
      else
        *(float4*)(OutC + (size_t)b * D_STATE * L_SEQ + (size_t)(r - D_STATE) * L_SEQ + n0) = v;
    }
  }
}

// ---------------------------------------------------------------------------
// K4: dt GEMM: DT[b][d][l] = sum_r DW[d][r] * XDBL[b][r][l]; K=64 (single tile)
// 64x64 tile, 256 threads, 4x4 per thread.
// ---------------------------------------------------------------------------
__global__ __launch_bounds__(256) void k_dt(const float* __restrict__ DW,
                                            const float* __restrict__ XDBL,
                                            float* __restrict__ DT) {
  const int b = blockIdx.z, bm = blockIdx.y, bn = blockIdx.x;
  __shared__ float As[64][68];  // k-major
  __shared__ float Bs[64][68];  // [k][n]
  const int tid = threadIdx.x;
  const int tx = tid & 15, ty = tid >> 4;
  const int row = tid >> 4;          // 0..15
  const int col = (tid & 15) << 2;   // 0..60
  const float* Bb = XDBL + (size_t)b * DT_RANK * L_SEQ;
#pragma unroll
  for (int q = 0; q < 4; ++q) {
    int r = q * 16 + row;
    float4 av = *(const float4*)(DW + (size_t)(bm * 64 + r) * DT_RANK + col);
    As[col + 0][r] = av.x; As[col + 1][r] = av.y;
    As[col + 2][r] = av.z; As[col + 3][r] = av.w;
    float4 bv = *(const float4*)(Bb + (size_t)r * L_SEQ + bn * 64 + col);
    *(float4*)&Bs[r][col] = bv;
  }
  __syncthreads();
  float acc[4][4] = {};
#pragma unroll 16
  for (int kk = 0; kk < 64; ++kk) {
    float4 a4 = *(const float4*)&As[kk][ty << 2];
    float4 b4 = *(const float4*)&Bs[kk][tx << 2];
    float a[4] = {a4.x, a4.y, a4.z, a4.w};
    float bb[4] = {b4.x, b4.y, b4.z, b4.w};
#pragma unroll
    for (int i = 0; i < 4; ++i)
#pragma unroll
      for (int j = 0; j < 4; ++j) acc[i][j] += a[i] * bb[j];
  }
  float* Cp = DT + (size_t)b * D_INNER * L_SEQ
                 + (size_t)(bm * 64 + (ty << 2)) * L_SEQ + bn * 64 + (tx << 2);
#pragma unroll
  for (int i = 0; i < 4; ++i) {
    float4 v = make_float4(acc[i][0], acc[i][1], acc[i][2], acc[i][3]);
    *(float4*)(Cp + (size_t)i * L_SEQ) = v;
  }
}

// ---------------------------------------------------------------------------
// K5: A = -exp(A_log)
// ---------------------------------------------------------------------------
__global__ __launch_bounds__(256) void k_A(const float* __restrict__ Alog,
                                           float* __restrict__ Aout) {
  int i = blockIdx.x * 256 + threadIdx.x;
  if (i < D_INNER * D_STATE) Aout[i] = -expf(Alog[i]);
}

extern "C" void kernel_launch(void* const* d_in, const int* in_sizes, int n_in,
                              void* d_out, int out_size, void* d_ws, size_t ws_size,
                              hipStream_t stream) {
  const float* hs   = (const float*)d_in[0];
  const float* ipw  = (const float*)d_in[1];
  const float* cw   = (const float*)d_in[2];
  const float* cb   = (const float*)d_in[3];
  const float* xpw  = (const float*)d_in[4];
  const float* dpw  = (const float*)d_in[5];
  const float* alog = (const float*)d_in[6];

  float* out    = (float*)d_out;
  float* dt_out = out + OFF_DT;
  float* a_out  = out + OFF_A;
  float* b_out  = out + OFF_B;
  float* c_out  = out + OFF_C;
  float* x_out  = out + OFF_X;

  // Stage pre-conv x in the dt region (exactly 4*2048*2048 floats);
  // it is consumed by k_conv before k_dt overwrites it (stream-ordered).
  float* xpre = dt_out;
  float* xdbl = (float*)d_ws;  // 4*64*2048 floats = 2 MB

  k_inproj<<<dim3(32, 32, 4), 256, 0, stream>>>(ipw, hs, xpre);
  k_conv<<<dim3(B_SZ * D_INNER), 512, 0, stream>>>(xpre, cw, cb, x_out);
  k_xproj<<<dim3(16, 3, 4), 256, 0, stream>>>(xpw, x_out, xdbl, b_out, c_out);
  k_dt<<<dim3(32, 32, 4), 256, 0, stream>>>(dpw, xdbl, dt_out);
  k_A<<<dim3((D_INNER * D_STATE + 255) / 256), 256, 0, stream>>>(alog, a_out);
}

// Round 2
// 212.716 us; speedup vs baseline: 2.7186x; 2.7186x over previous
//
#include <hip/hip_runtime.h>
#include <hip/hip_bf16.h>
#include <math.h>

#define D_MODEL 1024
#define D_STATE 16
#define D_CONV  4
#define D_INNER 2048
#define DT_RANK 64
#define B_SZ    4
#define L_SEQ   2048

// d_out layout (floats): dt | A | B | C | x
#define OFF_DT 0
#define OFF_A  (B_SZ * D_INNER * L_SEQ)
#define OFF_B  (OFF_A + D_INNER * D_STATE)
#define OFF_C  (OFF_B + B_SZ * D_STATE * L_SEQ)
#define OFF_X  (OFF_C + B_SZ * D_STATE * L_SEQ)

typedef __attribute__((ext_vector_type(8))) short bf16x8;
typedef __attribute__((ext_vector_type(4))) float f32x4;

static __device__ __forceinline__ unsigned short f2bf(float f) {
  __hip_bfloat16 h = __float2bfloat16(f);
  return *(unsigned short*)&h;
}

// ---------------------------------------------------------------------------
// K0: fp32 -> bf16 cast, 4 elems/thread
// ---------------------------------------------------------------------------
__global__ __launch_bounds__(256) void k_cast(const float4* __restrict__ in,
                                              ushort4* __restrict__ outp, int n4) {
  int i = blockIdx.x * 256 + threadIdx.x;
  if (i >= n4) return;
  float4 v = in[i];
  ushort4 o;
  o.x = f2bf(v.x); o.y = f2bf(v.y); o.z = f2bf(v.z); o.w = f2bf(v.w);
  outp[i] = o;
}

// ---------------------------------------------------------------------------
// K1: in_proj (x half) via bf16 MFMA.
// C[b][d][l] = sum_k W[d][k] * HS[b][l][k]   (NT GEMM, both K-major)
// 128x128 tile, BK=32, 256 thr = 4 waves (2x2), 16x16x32 MFMA, 4x4 frags/wave.
// Staging: global_load_lds width 16, pre-swizzled source (slot s^((row>>1)&3))
// so fragment ds_read_b128 is 2-way (free) instead of 8-way.
// ---------------------------------------------------------------------------
__global__ __launch_bounds__(256) void k_inproj_mfma(
    const unsigned short* __restrict__ Wb,   // [D_INNER][D_MODEL] bf16
    const unsigned short* __restrict__ HSb,  // [B][L][D_MODEL] bf16
    float* __restrict__ Cout) {              // [B][D_INNER][L]
  const int b  = blockIdx.z;
  const int bm = blockIdx.y;
  const int bn = blockIdx.x;
  __shared__ unsigned short As[128 * 32];
  __shared__ unsigned short Bs[128 * 32];
  const int tid  = threadIdx.x;
  const int wv   = tid >> 6;
  const int lane = tid & 63;
  const int wr = wv >> 1, wc = wv & 1;

  const int srow = tid >> 2;  // staging row within 64-row half
  const int ss   = tid & 3;   // staging 16B slot within row

  const unsigned short* Ag = Wb + (size_t)(bm * 128) * D_MODEL;
  const unsigned short* Bg = HSb + (size_t)b * L_SEQ * D_MODEL
                                 + (size_t)(bn * 128) * D_MODEL;

  f32x4 acc[4][4];
#pragma unroll
  for (int i = 0; i < 4; ++i)
#pragma unroll
    for (int j = 0; j < 4; ++j) acc[i][j] = (f32x4){0.f, 0.f, 0.f, 0.f};

  const int ksel = lane >> 4;
  const int frow = lane & 15;

  for (int k0 = 0; k0 < D_MODEL; k0 += 32) {
#pragma unroll
    for (int q = 0; q < 2; ++q) {
      int row = q * 64 + srow;
      int xs  = ss ^ ((row >> 1) & 3);
      const unsigned short* ga = Ag + (size_t)row * D_MODEL + k0 + xs * 8;
      const unsigned short* gb = Bg + (size_t)row * D_MODEL + k0 + xs * 8;
      unsigned short* la = As + (q * 256 + wv * 64) * 8;  // wave-uniform base
      unsigned short* lb = Bs + (q * 256 + wv * 64) * 8;
      __builtin_amdgcn_global_load_lds((const __attribute__((address_space(1))) void*)ga,
                                       (__attribute__((address_space(3))) void*)la, 16, 0, 0);
      __builtin_amdgcn_global_load_lds((const __attribute__((address_space(1))) void*)gb,
                                       (__attribute__((address_space(3))) void*)lb, 16, 0, 0);
    }
    __syncthreads();

    bf16x8 af[4], bfr[4];
#pragma unroll
    for (int m = 0; m < 4; ++m) {
      int row = wr * 64 + m * 16 + frow;
      af[m] = *(const bf16x8*)(As + (row * 4 + (ksel ^ ((row >> 1) & 3))) * 8);
    }
#pragma unroll
    for (int n = 0; n < 4; ++n) {
      int row = wc * 64 + n * 16 + frow;
      bfr[n] = *(const bf16x8*)(Bs + (row * 4 + (ksel ^ ((row >> 1) & 3))) * 8);
    }
#pragma unroll
    for (int m = 0; m < 4; ++m)
#pragma unroll
      for (int n = 0; n < 4; ++n)
        acc[m][n] = __builtin_amdgcn_mfma_f32_16x16x32_bf16(af[m], bfr[n], acc[m][n], 0, 0, 0);
    __syncthreads();
  }

  const int crow0 = (lane >> 4) * 4;
  const int ccol  = lane & 15;
  float* Cb = Cout + (size_t)b * D_INNER * L_SEQ;
#pragma unroll
  for (int m = 0; m < 4; ++m) {
    int gr0 = bm * 128 + wr * 64 + m * 16 + crow0;
#pragma unroll
    for (int n = 0; n < 4; ++n) {
      int gc = bn * 128 + wc * 64 + n * 16 + ccol;
#pragma unroll
      for (int i = 0; i < 4; ++i)
        Cb[(size_t)(gr0 + i) * L_SEQ + gc] = acc[m][n][i];
    }
  }
}

// ---------------------------------------------------------------------------
// K2: causal depthwise conv4 + bias + SiLU. One block per (b,d) row.
// ---------------------------------------------------------------------------
__global__ __launch_bounds__(512) void k_conv(const float* __restrict__ Xp,
                                              const float* __restrict__ CW,
                                              const float* __restrict__ CB,
                                              float* __restrict__ Xo) {
  const int bd = blockIdx.x;
  const int d  = bd & (D_INNER - 1);
  const float* row = Xp + (size_t)bd * L_SEQ;
  float* orow = Xo + (size_t)bd * L_SEQ;
  const float w0 = CW[d * 4 + 0], w1 = CW[d * 4 + 1];
  const float w2 = CW[d * 4 + 2], w3 = CW[d * 4 + 3];
  const float bias = CB[d];
  const int l0 = threadIdx.x << 2;
  float4 cur = *(const float4*)(row + l0);
  float p1 = 0.f, p2 = 0.f, p3 = 0.f;
  if (l0 >= 4) {
    float4 prev = *(const float4*)(row + l0 - 4);
    p3 = prev.y; p2 = prev.z; p1 = prev.w;
  }
  float v0 = w0 * p3    + w1 * p2    + w2 * p1    + w3 * cur.x + bias;
  float v1 = w0 * p2    + w1 * p1    + w2 * cur.x + w3 * cur.y + bias;
  float v2 = w0 * p1    + w1 * cur.x + w2 * cur.y + w3 * cur.z + bias;
  float v3 = w0 * cur.x + w1 * cur.y + w2 * cur.z + w3 * cur.w + bias;
  float4 o;
  o.x = v0 / (1.f + expf(-v0));
  o.y = v1 / (1.f + expf(-v1));
  o.z = v2 / (1.f + expf(-v2));
  o.w = v3 / (1.f + expf(-v3));
  *(float4*)(orow + l0) = o;
}

// ---------------------------------------------------------------------------
// K3: x_proj: C[b][e][l] = sum_d XW[e][d] * X[b][d][l]   (NN GEMM, fp32)
// ---------------------------------------------------------------------------
__global__ __launch_bounds__(256) void k_xproj(const float* __restrict__ XW,
                                               const float* __restrict__ X,
                                               float* __restrict__ XDBL,
                                               float* __restrict__ OutB,
                                               float* __restrict__ OutC) {
  const int b  = blockIdx.z;
  const int bm = blockIdx.y;   // 0..2
  const int bn = blockIdx.x;   // 0..15
  __shared__ float As[32][36];
  __shared__ float Bs[32][132];
  const int tid = threadIdx.x;
  const int tx = tid & 31, ty = tid >> 5;
  const int arow = tid >> 3;
  const int acol = (tid & 7) << 2;
  const float* Xb = X + (size_t)b * D_INNER * L_SEQ;
  const float* Ag = XW + (size_t)(bm * 32 + arow) * D_INNER + acol;
  float acc[4][4] = {};

  for (int k0 = 0; k0 < D_INNER; k0 += 32) {
    float4 av = *(const float4*)(Ag + k0);
    As[acol + 0][arow] = av.x; As[acol + 1][arow] = av.y;
    As[acol + 2][arow] = av.z; As[acol + 3][arow] = av.w;
#pragma unroll
    for (int q = 0; q < 4; ++q) {
      int brow = q * 8 + (tid >> 5);
      int bcol = (tid & 31) << 2;
      float4 bv = *(const float4*)(Xb + (size_t)(k0 + brow) * L_SEQ + bn * 128 + bcol);
      *(float4*)&Bs[brow][bcol] = bv;
    }
    __syncthreads();
#pragma unroll
    for (int kk = 0; kk < 32; ++kk) {
      float4 a4 = *(const float4*)&As[kk][ty << 2];
      float4 b4 = *(const float4*)&Bs[kk][tx << 2];
      float a[4] = {a4.x, a4.y, a4.z, a4.w};
      float bb[4] = {b4.x, b4.y, b4.z, b4.w};
#pragma unroll
      for (int i = 0; i < 4; ++i)
#pragma unroll
        for (int j = 0; j < 4; ++j) acc[i][j] += a[i] * bb[j];
    }
    __syncthreads();
  }

  const int n0 = bn * 128 + (tx << 2);
#pragma unroll
  for (int i = 0; i < 4; ++i) {
    int e = bm * 32 + (ty << 2) + i;
    float4 v = make_float4(acc[i][0], acc[i][1], acc[i][2], acc[i][3]);
    if (bm < 2) {
      *(float4*)(XDBL + (size_t)b * DT_RANK * L_SEQ + (size_t)e * L_SEQ + n0) = v;
    } else {
      int r = e - DT_RANK;
      if (r < D_STATE)
        *(float4*)(OutB + (size_t)b * D_STATE * L_SEQ + (size_t)r * L_SEQ + n0) = v;
      else
        *(float4*)(OutC + (size_t)b * D_STATE * L_SEQ + (size_t)(r - D_STATE) * L_SEQ + n0) = v;
    }
  }
}

// ---------------------------------------------------------------------------
// K4: dt GEMM: DT[b][d][l] = sum_r DW[d][r] * XDBL[b][r][l]; K=64 (fp32)
// ---------------------------------------------------------------------------
__global__ __launch_bounds__(256) void k_dt(const float* __restrict__ DW,
                                            const float* __restrict__ XDBL,
                                            float* __restrict__ DT) {
  const int b = blockIdx.z, bm = blockIdx.y, bn = blockIdx.x;
  __shared__ float As[64][68];
  __shared__ float Bs[64][68];
  const int tid = threadIdx.x;
  const int tx = tid & 15, ty = tid >> 4;
  const int row = tid >> 4;
  const int col = (tid & 15) << 2;
  const float* Bb = XDBL + (size_t)b * DT_RANK * L_SEQ;
#pragma unroll
  for (int q = 0; q < 4; ++q) {
    int r = q * 16 + row;
    float4 av = *(const float4*)(DW + (size_t)(bm * 64 + r) * DT_RANK + col);
    As[col + 0][r] = av.x; As[col + 1][r] = av.y;
    As[col + 2][r] = av.z; As[col + 3][r] = av.w;
    float4 bv = *(const float4*)(Bb + (size_t)r * L_SEQ + bn * 64 + col);
    *(float4*)&Bs[r][col] = bv;
  }
  __syncthreads();
  float acc[4][4] = {};
#pragma unroll 16
  for (int kk = 0; kk < 64; ++kk) {
    float4 a4 = *(const float4*)&As[kk][ty << 2];
    float4 b4 = *(const float4*)&Bs[kk][tx << 2];
    float a[4] = {a4.x, a4.y, a4.z, a4.w};
    float bb[4] = {b4.x, b4.y, b4.z, b4.w};
#pragma unroll
    for (int i = 0; i < 4; ++i)
#pragma unroll
      for (int j = 0; j < 4; ++j) acc[i][j] += a[i] * bb[j];
  }
  float* Cp = DT + (size_t)b * D_INNER * L_SEQ
                 + (size_t)(bm * 64 + (ty << 2)) * L_SEQ + bn * 64 + (tx << 2);
#pragma unroll
  for (int i = 0; i < 4; ++i) {
    float4 v = make_float4(acc[i][0], acc[i][1], acc[i][2], acc[i][3]);
    *(float4*)(Cp + (size_t)i * L_SEQ) = v;
  }
}

// ---------------------------------------------------------------------------
// K5: A = -exp(A_log)
// ---------------------------------------------------------------------------
__global__ __launch_bounds__(256) void k_A(const float* __restrict__ Alog,
                                           float* __restrict__ Aout) {
  int i = blockIdx.x * 256 + threadIdx.x;
  if (i < D_INNER * D_STATE) Aout[i] = -expf(Alog[i]);
}

extern "C" void kernel_launch(void* const* d_in, const int* in_sizes, int n_in,
                              void* d_out, int out_size, void* d_ws, size_t ws_size,
                              hipStream_t stream) {
  const float* hs   = (const float*)d_in[0];
  const float* ipw  = (const float*)d_in[1];
  const float* cw   = (const float*)d_in[2];
  const float* cb   = (const float*)d_in[3];
  const float* xpw  = (const float*)d_in[4];
  const float* dpw  = (const float*)d_in[5];
  const float* alog = (const float*)d_in[6];

  float* out    = (float*)d_out;
  float* dt_out = out + OFF_DT;
  float* a_out  = out + OFF_A;
  float* b_out  = out + OFF_B;
  float* c_out  = out + OFF_C;
  float* x_out  = out + OFF_X;

  // Scratch plan:
  //  - bf16 HS (16.8 MB) + bf16 W-half (4.2 MB) live in the x region of d_out
  //    (written later by k_conv, consumed by k_inproj_mfma before that).
  //  - xpre (pre-conv x, fp32, 67 MB) lives in the dt region (overwritten by k_dt).
  //  - xdbl (2 MB) in d_ws.
  unsigned short* bfHS = (unsigned short*)x_out;
  unsigned short* bfW  = bfHS + (size_t)B_SZ * L_SEQ * D_MODEL;
  float* xpre = dt_out;
  float* xdbl = (float*)d_ws;

  const int n4_hs = B_SZ * L_SEQ * D_MODEL / 4;
  const int n4_w  = D_INNER * D_MODEL / 4;
  k_cast<<<dim3((n4_hs + 255) / 256), 256, 0, stream>>>((const float4*)hs, (ushort4*)bfHS, n4_hs);
  k_cast<<<dim3((n4_w + 255) / 256), 256, 0, stream>>>((const float4*)ipw, (ushort4*)bfW, n4_w);

  k_inproj_mfma<<<dim3(16, 16, 4), 256, 0, stream>>>(bfW, bfHS, xpre);
  k_conv<<<dim3(B_SZ * D_INNER), 512, 0, stream>>>(xpre, cw, cb, x_out);
  k_xproj<<<dim3(16, 3, 4), 256, 0, stream>>>(xpw, x_out, xdbl, b_out, c_out);
  k_dt<<<dim3(32, 32, 4), 256, 0, stream>>>(dpw, xdbl, dt_out);
  k_A<<<dim3((D_INNER * D_STATE + 255) / 256), 256, 0, stream>>>(alog, a_out);
}

// Round 3
// 162.376 us; speedup vs baseline: 3.5614x; 1.3100x over previous
//
#include <hip/hip_runtime.h>
#include <hip/hip_bf16.h>
#include <math.h>

#define D_MODEL 1024
#define D_STATE 16
#define D_CONV  4
#define D_INNER 2048
#define DT_RANK 64
#define B_SZ    4
#define L_SEQ   2048

// d_out layout (floats): dt | A | B | C | x
#define OFF_DT 0
#define OFF_A  (B_SZ * D_INNER * L_SEQ)
#define OFF_B  (OFF_A + D_INNER * D_STATE)
#define OFF_C  (OFF_B + B_SZ * D_STATE * L_SEQ)
#define OFF_X  (OFF_C + B_SZ * D_STATE * L_SEQ)

typedef __attribute__((ext_vector_type(8))) short bf16x8;
typedef __attribute__((ext_vector_type(4))) float f32x4;
typedef unsigned short ushort_t;
typedef unsigned int uint_t;

static __device__ __forceinline__ ushort_t f2bf(float f) {
  __hip_bfloat16 h = __float2bfloat16(f);
  return *(ushort_t*)&h;
}

// ---------------------------------------------------------------------------
// K0: fp32 -> bf16 cast, 4 elems/thread
// ---------------------------------------------------------------------------
__global__ __launch_bounds__(256) void k_cast(const float4* __restrict__ in,
                                              ushort4* __restrict__ outp, int n4) {
  int i = blockIdx.x * 256 + threadIdx.x;
  if (i >= n4) return;
  float4 v = in[i];
  ushort4 o;
  o.x = f2bf(v.x); o.y = f2bf(v.y); o.z = f2bf(v.z); o.w = f2bf(v.w);
  outp[i] = o;
}

// ---------------------------------------------------------------------------
// K1: in_proj (x half) via bf16 MFMA. (unchanged from round 2)
// ---------------------------------------------------------------------------
__global__ __launch_bounds__(256) void k_inproj_mfma(
    const ushort_t* __restrict__ Wb,   // [D_INNER][D_MODEL] bf16
    const ushort_t* __restrict__ HSb,  // [B][L][D_MODEL] bf16
    float* __restrict__ Cout) {        // [B][D_INNER][L]
  const int b  = blockIdx.z;
  const int bm = blockIdx.y;
  const int bn = blockIdx.x;
  __shared__ ushort_t As[128 * 32];
  __shared__ ushort_t Bs[128 * 32];
  const int tid  = threadIdx.x;
  const int wv   = tid >> 6;
  const int lane = tid & 63;
  const int wr = wv >> 1, wc = wv & 1;

  const int srow = tid >> 2;
  const int ss   = tid & 3;

  const ushort_t* Ag = Wb + (size_t)(bm * 128) * D_MODEL;
  const ushort_t* Bg = HSb + (size_t)b * L_SEQ * D_MODEL
                           + (size_t)(bn * 128) * D_MODEL;

  f32x4 acc[4][4];
#pragma unroll
  for (int i = 0; i < 4; ++i)
#pragma unroll
    for (int j = 0; j < 4; ++j) acc[i][j] = (f32x4){0.f, 0.f, 0.f, 0.f};

  const int ksel = lane >> 4;
  const int frow = lane & 15;

  for (int k0 = 0; k0 < D_MODEL; k0 += 32) {
#pragma unroll
    for (int q = 0; q < 2; ++q) {
      int row = q * 64 + srow;
      int xs  = ss ^ ((row >> 1) & 3);
      const ushort_t* ga = Ag + (size_t)row * D_MODEL + k0 + xs * 8;
      const ushort_t* gb = Bg + (size_t)row * D_MODEL + k0 + xs * 8;
      ushort_t* la = As + (q * 256 + wv * 64) * 8;
      ushort_t* lb = Bs + (q * 256 + wv * 64) * 8;
      __builtin_amdgcn_global_load_lds((const __attribute__((address_space(1))) void*)ga,
                                       (__attribute__((address_space(3))) void*)la, 16, 0, 0);
      __builtin_amdgcn_global_load_lds((const __attribute__((address_space(1))) void*)gb,
                                       (__attribute__((address_space(3))) void*)lb, 16, 0, 0);
    }
    __syncthreads();

    bf16x8 af[4], bfr[4];
#pragma unroll
    for (int m = 0; m < 4; ++m) {
      int row = wr * 64 + m * 16 + frow;
      af[m] = *(const bf16x8*)(As + (row * 4 + (ksel ^ ((row >> 1) & 3))) * 8);
    }
#pragma unroll
    for (int n = 0; n < 4; ++n) {
      int row = wc * 64 + n * 16 + frow;
      bfr[n] = *(const bf16x8*)(Bs + (row * 4 + (ksel ^ ((row >> 1) & 3))) * 8);
    }
#pragma unroll
    for (int m = 0; m < 4; ++m)
#pragma unroll
      for (int n = 0; n < 4; ++n)
        acc[m][n] = __builtin_amdgcn_mfma_f32_16x16x32_bf16(af[m], bfr[n], acc[m][n], 0, 0, 0);
    __syncthreads();
  }

  const int crow0 = (lane >> 4) * 4;
  const int ccol  = lane & 15;
  float* Cb = Cout + (size_t)b * D_INNER * L_SEQ;
#pragma unroll
  for (int m = 0; m < 4; ++m) {
    int gr0 = bm * 128 + wr * 64 + m * 16 + crow0;
#pragma unroll
    for (int n = 0; n < 4; ++n) {
      int gc = bn * 128 + wc * 64 + n * 16 + ccol;
#pragma unroll
      for (int i = 0; i < 4; ++i)
        Cb[(size_t)(gr0 + i) * L_SEQ + gc] = acc[m][n][i];
    }
  }
}

// ---------------------------------------------------------------------------
// K2: causal depthwise conv4 + bias + SiLU. One block per (b,d) row.
// ---------------------------------------------------------------------------
__global__ __launch_bounds__(512) void k_conv(const float* __restrict__ Xp,
                                              const float* __restrict__ CW,
                                              const float* __restrict__ CB,
                                              float* __restrict__ Xo) {
  const int bd = blockIdx.x;
  const int d  = bd & (D_INNER - 1);
  const float* row = Xp + (size_t)bd * L_SEQ;
  float* orow = Xo + (size_t)bd * L_SEQ;
  const float w0 = CW[d * 4 + 0], w1 = CW[d * 4 + 1];
  const float w2 = CW[d * 4 + 2], w3 = CW[d * 4 + 3];
  const float bias = CB[d];
  const int l0 = threadIdx.x << 2;
  float4 cur = *(const float4*)(row + l0);
  float p1 = 0.f, p2 = 0.f, p3 = 0.f;
  if (l0 >= 4) {
    float4 prev = *(const float4*)(row + l0 - 4);
    p3 = prev.y; p2 = prev.z; p1 = prev.w;
  }
  float v0 = w0 * p3    + w1 * p2    + w2 * p1    + w3 * cur.x + bias;
  float v1 = w0 * p2    + w1 * p1    + w2 * cur.x + w3 * cur.y + bias;
  float v2 = w0 * p1    + w1 * cur.x + w2 * cur.y + w3 * cur.z + bias;
  float v3 = w0 * cur.x + w1 * cur.y + w2 * cur.z + w3 * cur.w + bias;
  float4 o;
  o.x = v0 / (1.f + expf(-v0));
  o.y = v1 / (1.f + expf(-v1));
  o.z = v2 / (1.f + expf(-v2));
  o.w = v3 / (1.f + expf(-v3));
  *(float4*)(orow + l0) = o;
}

// ---------------------------------------------------------------------------
// K3: x_proj via bf16 MFMA, split-K, in-kernel B transpose.
// C[b][e][l] = sum_d XW[e][d] * X[b][d][l],  M=96, N=2048, K=2048.
// Grid (ln=16, sk=8, b=4) = 512 blocks, 256 thr (4 waves 2x2).
// A: XWb bf16 [96][2048] staged [96][40-pad] LDS.
// B: X fp32 [d][l]: coalesced float4 from 2 adjacent d-rows -> bf16 pair
//    -> ds_write_b32 into Bs[n=128][k=32 pad 34 ushorts].
// Epilogue: fp32 atomicAdd into xdbl / B_mat / C_mat (zeroed beforehand).
// ---------------------------------------------------------------------------
__global__ __launch_bounds__(256) void k_xproj_mfma(
    const ushort_t* __restrict__ XWb,  // [96][2048] bf16
    const float* __restrict__ X,       // [B][D_INNER][L]
    float* __restrict__ XDBL,          // [B][64][L] fp32 (atomic)
    float* __restrict__ OutB,          // [B][16][L]  (atomic)
    float* __restrict__ OutC) {        // [B][16][L]  (atomic)
  const int ln = blockIdx.x;   // 0..15
  const int sk = blockIdx.y;   // 0..7
  const int b  = blockIdx.z;
  __shared__ ushort_t As[96 * 40];
  __shared__ ushort_t Bs[128 * 34];
  const int tid  = threadIdx.x;
  const int wv   = tid >> 6;
  const int lane = tid & 63;
  const int wr = wv >> 1, wc = wv & 1;
  const int ksel = lane >> 4;
  const int frow = lane & 15;

  const float* Xb = X + (size_t)b * D_INNER * L_SEQ + (size_t)ln * 128;

  f32x4 acc[3][4];
#pragma unroll
  for (int i = 0; i < 3; ++i)
#pragma unroll
    for (int j = 0; j < 4; ++j) acc[i][j] = (f32x4){0.f, 0.f, 0.f, 0.f};

  for (int k0 = 0; k0 < 256; k0 += 32) {
    const int koff = sk * 256 + k0;
    // ---- stage A tile [96][32] ----
    {
      int task = tid;
      int row = task >> 2, s = task & 3;
      bf16x8 v = *(const bf16x8*)(XWb + (size_t)row * D_INNER + koff + s * 8);
      *(bf16x8*)(As + row * 40 + s * 8) = v;
      if (tid < 128) {
        int row2 = 64 + (tid >> 2);
        bf16x8 v2 = *(const bf16x8*)(XWb + (size_t)row2 * D_INNER + koff + s * 8);
        *(bf16x8*)(As + row2 * 40 + s * 8) = v2;
      }
    }
    // ---- stage B tile [32 k][128 n] transposed -> Bs[n][k] ----
#pragma unroll
    for (int j = 0; j < 2; ++j) {
      int u = tid + 256 * j;
      int n4 = u & 31;           // n0 = 4*n4
      int kp = u >> 5;           // k-pair 0..15
      const float* g0 = Xb + (size_t)(koff + 2 * kp) * L_SEQ + 4 * n4;
      float4 x0 = *(const float4*)g0;
      float4 x1 = *(const float4*)(g0 + L_SEQ);
      float e0[4] = {x0.x, x0.y, x0.z, x0.w};
      float e1[4] = {x1.x, x1.y, x1.z, x1.w};
#pragma unroll
      for (int i = 0; i < 4; ++i) {
        uint_t pk = (uint_t)f2bf(e0[i]) | ((uint_t)f2bf(e1[i]) << 16);
        int n = 4 * n4 + i;
        *(uint_t*)(Bs + n * 34 + 2 * kp) = pk;
      }
    }
    __syncthreads();

    // ---- fragments ----
    bf16x8 af[3], bfr[4];
#pragma unroll
    for (int mi = 0; mi < 3; ++mi) {
      int row = wr * 48 + mi * 16 + frow;
      af[mi] = *(const bf16x8*)(As + row * 40 + ksel * 8);
    }
#pragma unroll
    for (int ni = 0; ni < 4; ++ni) {
      int n = wc * 64 + ni * 16 + frow;
      const uint_t* p = (const uint_t*)(Bs + n * 34);
      union { uint_t u[4]; bf16x8 v; } fr;
#pragma unroll
      for (int q = 0; q < 4; ++q) fr.u[q] = p[ksel * 4 + q];
      bfr[ni] = fr.v;
    }
#pragma unroll
    for (int mi = 0; mi < 3; ++mi)
#pragma unroll
      for (int ni = 0; ni < 4; ++ni)
        acc[mi][ni] = __builtin_amdgcn_mfma_f32_16x16x32_bf16(af[mi], bfr[ni], acc[mi][ni], 0, 0, 0);
    __syncthreads();
  }

  // ---- epilogue: atomic accumulate ----
  const int crow0 = (lane >> 4) * 4;
  const int ccol  = lane & 15;
#pragma unroll
  for (int mi = 0; mi < 3; ++mi) {
    int e0 = wr * 48 + mi * 16 + crow0;  // wave-uniform target region per (wr,mi)
    float* base;
    int eoff;
    if (e0 < 64)      { base = XDBL + (size_t)b * 64 * L_SEQ; eoff = e0; }
    else if (e0 < 80) { base = OutB + (size_t)b * D_STATE * L_SEQ; eoff = e0 - 64; }
    else              { base = OutC + (size_t)b * D_STATE * L_SEQ; eoff = e0 - 80; }
#pragma unroll
    for (int ni = 0; ni < 4; ++ni) {
      int l = ln * 128 + wc * 64 + ni * 16 + ccol;
#pragma unroll
      for (int r = 0; r < 4; ++r)
        atomicAdd(base + (size_t)(eoff + r) * L_SEQ + l, acc[mi][ni][r]);
    }
  }
}

// ---------------------------------------------------------------------------
// K4: dt GEMM: DT[b][d][l] = sum_r DW[d][r] * XDBL[b][r][l]; K=64 (fp32)
// ---------------------------------------------------------------------------
__global__ __launch_bounds__(256) void k_dt(const float* __restrict__ DW,
                                            const float* __restrict__ XDBL,
                                            float* __restrict__ DT) {
  const int b = blockIdx.z, bm = blockIdx.y, bn = blockIdx.x;
  __shared__ float As[64][68];
  __shared__ float Bs[64][68];
  const int tid = threadIdx.x;
  const int tx = tid & 15, ty = tid >> 4;
  const int row = tid >> 4;
  const int col = (tid & 15) << 2;
  const float* Bb = XDBL + (size_t)b * DT_RANK * L_SEQ;
#pragma unroll
  for (int q = 0; q < 4; ++q) {
    int r = q * 16 + row;
    float4 av = *(const float4*)(DW + (size_t)(bm * 64 + r) * DT_RANK + col);
    As[col + 0][r] = av.x; As[col + 1][r] = av.y;
    As[col + 2][r] = av.z; As[col + 3][r] = av.w;
    float4 bv = *(const float4*)(Bb + (size_t)r * L_SEQ + bn * 64 + col);
    *(float4*)&Bs[r][col] = bv;
  }
  __syncthreads();
  float acc[4][4] = {};
#pragma unroll 16
  for (int kk = 0; kk < 64; ++kk) {
    float4 a4 = *(const float4*)&As[kk][ty << 2];
    float4 b4 = *(const float4*)&Bs[kk][tx << 2];
    float a[4] = {a4.x, a4.y, a4.z, a4.w};
    float bb[4] = {b4.x, b4.y, b4.z, b4.w};
#pragma unroll
    for (int i = 0; i < 4; ++i)
#pragma unroll
      for (int j = 0; j < 4; ++j) acc[i][j] += a[i] * bb[j];
  }
  float* Cp = DT + (size_t)b * D_INNER * L_SEQ
                 + (size_t)(bm * 64 + (ty << 2)) * L_SEQ + bn * 64 + (tx << 2);
#pragma unroll
  for (int i = 0; i < 4; ++i) {
    float4 v = make_float4(acc[i][0], acc[i][1], acc[i][2], acc[i][3]);
    *(float4*)(Cp + (size_t)i * L_SEQ) = v;
  }
}

// ---------------------------------------------------------------------------
// K5: A = -exp(A_log)
// ---------------------------------------------------------------------------
__global__ __launch_bounds__(256) void k_A(const float* __restrict__ Alog,
                                           float* __restrict__ Aout) {
  int i = blockIdx.x * 256 + threadIdx.x;
  if (i < D_INNER * D_STATE) Aout[i] = -expf(Alog[i]);
}

extern "C" void kernel_launch(void* const* d_in, const int* in_sizes, int n_in,
                              void* d_out, int out_size, void* d_ws, size_t ws_size,
                              hipStream_t stream) {
  const float* hs   = (const float*)d_in[0];
  const float* ipw  = (const float*)d_in[1];
  const float* cw   = (const float*)d_in[2];
  const float* cb   = (const float*)d_in[3];
  const float* xpw  = (const float*)d_in[4];
  const float* dpw  = (const float*)d_in[5];
  const float* alog = (const float*)d_in[6];

  float* out    = (float*)d_out;
  float* dt_out = out + OFF_DT;
  float* a_out  = out + OFF_A;
  float* b_out  = out + OFF_B;
  float* c_out  = out + OFF_C;
  float* x_out  = out + OFF_X;

  // Scratch plan:
  //  - bf16 HS (16.8 MB) + bf16 W-half (4.2 MB) in x region of d_out (dead
  //    after k_inproj; conv overwrites).
  //  - xpre (pre-conv x, fp32, 67 MB) in dt region (overwritten by k_dt).
  //  - d_ws: xdbl fp32 (2 MB) | XWb bf16 (384 KB).
  unsigned short* bfHS = (unsigned short*)x_out;
  unsigned short* bfW  = bfHS + (size_t)B_SZ * L_SEQ * D_MODEL;
  float* xpre = dt_out;
  float* xdbl = (float*)d_ws;
  unsigned short* xwb = (unsigned short*)((char*)d_ws + (size_t)B_SZ * DT_RANK * L_SEQ * 4);

  const int n4_hs = B_SZ * L_SEQ * D_MODEL / 4;
  const int n4_w  = D_INNER * D_MODEL / 4;
  const int n4_xw = (DT_RANK + 2 * D_STATE) * D_INNER / 4;
  k_cast<<<dim3((n4_hs + 255) / 256), 256, 0, stream>>>((const float4*)hs, (ushort4*)bfHS, n4_hs);
  k_cast<<<dim3((n4_w + 255) / 256), 256, 0, stream>>>((const float4*)ipw, (ushort4*)bfW, n4_w);
  k_cast<<<dim3((n4_xw + 255) / 256), 256, 0, stream>>>((const float4*)xpw, (ushort4*)xwb, n4_xw);

  // Zero split-K accumulation targets (xdbl in ws; B and C contiguous in out).
  hipMemsetAsync(xdbl, 0, (size_t)B_SZ * DT_RANK * L_SEQ * 4, stream);
  hipMemsetAsync(b_out, 0, (size_t)2 * B_SZ * D_STATE * L_SEQ * 4, stream);

  k_inproj_mfma<<<dim3(16, 16, 4), 256, 0, stream>>>(bfW, bfHS, xpre);
  k_conv<<<dim3(B_SZ * D_INNER), 512, 0, stream>>>(xpre, cw, cb, x_out);
  k_xproj_mfma<<<dim3(16, 8, 4), 256, 0, stream>>>(xwb, x_out, xdbl, b_out, c_out);
  k_dt<<<dim3(32, 32, 4), 256, 0, stream>>>(dpw, xdbl, dt_out);
  k_A<<<dim3((D_INNER * D_STATE + 255) / 256), 256, 0, stream>>>(alog, a_out);
}

// Round 4
// 157.385 us; speedup vs baseline: 3.6744x; 1.0317x over previous
//
#include <hip/hip_runtime.h>
#include <hip/hip_bf16.h>
#include <math.h>

#define D_MODEL 1024
#define D_STATE 16
#define D_CONV  4
#define D_INNER 2048
#define DT_RANK 64
#define B_SZ    4
#define L_SEQ   2048

// d_out layout (floats): dt | A | B | C | x
#define OFF_DT 0
#define OFF_A  (B_SZ * D_INNER * L_SEQ)
#define OFF_B  (OFF_A + D_INNER * D_STATE)
#define OFF_C  (OFF_B + B_SZ * D_STATE * L_SEQ)
#define OFF_X  (OFF_C + B_SZ * D_STATE * L_SEQ)

typedef __attribute__((ext_vector_type(8))) short bf16x8;
typedef __attribute__((ext_vector_type(4))) float f32x4;
typedef unsigned short ushort_t;
typedef unsigned int uint_t;

static __device__ __forceinline__ ushort_t f2bf(float f) {
  __hip_bfloat16 h = __float2bfloat16(f);
  return *(ushort_t*)&h;
}

// ---------------------------------------------------------------------------
// K0: fused prep — bf16 casts (hs, in_proj x-half, x_proj_w) + zero of the
// split-K accumulation targets (xdbl, B|C region). One launch, float4 tasks.
// ---------------------------------------------------------------------------
#define N4_HS   (B_SZ * L_SEQ * D_MODEL / 4)                 // 2097152
#define N4_W    (D_INNER * D_MODEL / 4)                      // 524288
#define N4_XW   ((DT_RANK + 2 * D_STATE) * D_INNER / 4)      // 49152
#define N4_Z0   (B_SZ * DT_RANK * L_SEQ / 4)                 // 131072 (xdbl)
#define N4_Z1   (2 * B_SZ * D_STATE * L_SEQ / 4)             // 65536  (B|C)
#define N4_TOT  (N4_HS + N4_W + N4_XW + N4_Z0 + N4_Z1)

__global__ __launch_bounds__(256) void k_prep(
    const float4* __restrict__ hs, const float4* __restrict__ ipw,
    const float4* __restrict__ xpw,
    ushort4* __restrict__ bfHS, ushort4* __restrict__ bfW,
    ushort4* __restrict__ xwb,
    float4* __restrict__ z0, float4* __restrict__ z1) {
  int i = blockIdx.x * 256 + threadIdx.x;
  if (i < N4_HS) {
    float4 v = hs[i];
    ushort4 o; o.x = f2bf(v.x); o.y = f2bf(v.y); o.z = f2bf(v.z); o.w = f2bf(v.w);
    bfHS[i] = o;
    return;
  }
  i -= N4_HS;
  if (i < N4_W) {
    float4 v = ipw[i];
    ushort4 o; o.x = f2bf(v.x); o.y = f2bf(v.y); o.z = f2bf(v.z); o.w = f2bf(v.w);
    bfW[i] = o;
    return;
  }
  i -= N4_W;
  if (i < N4_XW) {
    float4 v = xpw[i];
    ushort4 o; o.x = f2bf(v.x); o.y = f2bf(v.y); o.z = f2bf(v.z); o.w = f2bf(v.w);
    xwb[i] = o;
    return;
  }
  i -= N4_XW;
  if (i < N4_Z0) { z0[i] = (float4){0.f, 0.f, 0.f, 0.f}; return; }
  i -= N4_Z0;
  if (i < N4_Z1) z1[i] = (float4){0.f, 0.f, 0.f, 0.f};
}

// ---------------------------------------------------------------------------
// K1: in_proj (x half) via bf16 MFMA, XCD-swizzled block mapping.
// C[b][d][l] = sum_k W[d][k] * HS[b][l][k]   (NT GEMM, both K-major)
// ---------------------------------------------------------------------------
__global__ __launch_bounds__(256) void k_inproj_mfma(
    const ushort_t* __restrict__ Wb,   // [D_INNER][D_MODEL] bf16
    const ushort_t* __restrict__ HSb,  // [B][L][D_MODEL] bf16
    float* __restrict__ Cout) {        // [B][D_INNER][L]
  // XCD-aware bijective swizzle: nwg = 16*16*4 = 1024, 1024 % 8 == 0.
  const int flat = blockIdx.x + 16 * blockIdx.y + 256 * blockIdx.z;
  const int swz  = (flat & 7) * 128 + (flat >> 3);
  const int bn = swz & 15;
  const int bm = (swz >> 4) & 15;
  const int b  = swz >> 8;

  __shared__ ushort_t As[128 * 32];
  __shared__ ushort_t Bs[128 * 32];
  const int tid  = threadIdx.x;
  const int wv   = tid >> 6;
  const int lane = tid & 63;
  const int wr = wv >> 1, wc = wv & 1;

  const int srow = tid >> 2;
  const int ss   = tid & 3;

  const ushort_t* Ag = Wb + (size_t)(bm * 128) * D_MODEL;
  const ushort_t* Bg = HSb + (size_t)b * L_SEQ * D_MODEL
                           + (size_t)(bn * 128) * D_MODEL;

  f32x4 acc[4][4];
#pragma unroll
  for (int i = 0; i < 4; ++i)
#pragma unroll
    for (int j = 0; j < 4; ++j) acc[i][j] = (f32x4){0.f, 0.f, 0.f, 0.f};

  const int ksel = lane >> 4;
  const int frow = lane & 15;

  for (int k0 = 0; k0 < D_MODEL; k0 += 32) {
#pragma unroll
    for (int q = 0; q < 2; ++q) {
      int row = q * 64 + srow;
      int xs  = ss ^ ((row >> 1) & 3);
      const ushort_t* ga = Ag + (size_t)row * D_MODEL + k0 + xs * 8;
      const ushort_t* gb = Bg + (size_t)row * D_MODEL + k0 + xs * 8;
      ushort_t* la = As + (q * 256 + wv * 64) * 8;
      ushort_t* lb = Bs + (q * 256 + wv * 64) * 8;
      __builtin_amdgcn_global_load_lds((const __attribute__((address_space(1))) void*)ga,
                                       (__attribute__((address_space(3))) void*)la, 16, 0, 0);
      __builtin_amdgcn_global_load_lds((const __attribute__((address_space(1))) void*)gb,
                                       (__attribute__((address_space(3))) void*)lb, 16, 0, 0);
    }
    __syncthreads();

    bf16x8 af[4], bfr[4];
#pragma unroll
    for (int m = 0; m < 4; ++m) {
      int row = wr * 64 + m * 16 + frow;
      af[m] = *(const bf16x8*)(As + (row * 4 + (ksel ^ ((row >> 1) & 3))) * 8);
    }
#pragma unroll
    for (int n = 0; n < 4; ++n) {
      int row = wc * 64 + n * 16 + frow;
      bfr[n] = *(const bf16x8*)(Bs + (row * 4 + (ksel ^ ((row >> 1) & 3))) * 8);
    }
#pragma unroll
    for (int m = 0; m < 4; ++m)
#pragma unroll
      for (int n = 0; n < 4; ++n)
        acc[m][n] = __builtin_amdgcn_mfma_f32_16x16x32_bf16(af[m], bfr[n], acc[m][n], 0, 0, 0);
    __syncthreads();
  }

  const int crow0 = (lane >> 4) * 4;
  const int ccol  = lane & 15;
  float* Cb = Cout + (size_t)b * D_INNER * L_SEQ;
#pragma unroll
  for (int m = 0; m < 4; ++m) {
    int gr0 = bm * 128 + wr * 64 + m * 16 + crow0;
#pragma unroll
    for (int n = 0; n < 4; ++n) {
      int gc = bn * 128 + wc * 64 + n * 16 + ccol;
#pragma unroll
      for (int i = 0; i < 4; ++i)
        Cb[(size_t)(gr0 + i) * L_SEQ + gc] = acc[m][n][i];
    }
  }
}

// ---------------------------------------------------------------------------
// K2: causal depthwise conv4 + bias + SiLU. One block per (b,d) row.
// ---------------------------------------------------------------------------
__global__ __launch_bounds__(512) void k_conv(const float* __restrict__ Xp,
                                              const float* __restrict__ CW,
                                              const float* __restrict__ CB,
                                              float* __restrict__ Xo) {
  const int bd = blockIdx.x;
  const int d  = bd & (D_INNER - 1);
  const float* row = Xp + (size_t)bd * L_SEQ;
  float* orow = Xo + (size_t)bd * L_SEQ;
  const float w0 = CW[d * 4 + 0], w1 = CW[d * 4 + 1];
  const float w2 = CW[d * 4 + 2], w3 = CW[d * 4 + 3];
  const float bias = CB[d];
  const int l0 = threadIdx.x << 2;
  float4 cur = *(const float4*)(row + l0);
  float p1 = 0.f, p2 = 0.f, p3 = 0.f;
  if (l0 >= 4) {
    float4 prev = *(const float4*)(row + l0 - 4);
    p3 = prev.y; p2 = prev.z; p1 = prev.w;
  }
  float v0 = w0 * p3    + w1 * p2    + w2 * p1    + w3 * cur.x + bias;
  float v1 = w0 * p2    + w1 * p1    + w2 * cur.x + w3 * cur.y + bias;
  float v2 = w0 * p1    + w1 * cur.x + w2 * cur.y + w3 * cur.z + bias;
  float v3 = w0 * cur.x + w1 * cur.y + w2 * cur.z + w3 * cur.w + bias;
  float4 o;
  o.x = v0 / (1.f + expf(-v0));
  o.y = v1 / (1.f + expf(-v1));
  o.z = v2 / (1.f + expf(-v2));
  o.w = v3 / (1.f + expf(-v3));
  *(float4*)(orow + l0) = o;
}

// ---------------------------------------------------------------------------
// K3: x_proj via bf16 MFMA, split-K, in-kernel B transpose, atomic epilogue.
// ---------------------------------------------------------------------------
__global__ __launch_bounds__(256) void k_xproj_mfma(
    const ushort_t* __restrict__ XWb,  // [96][2048] bf16
    const float* __restrict__ X,       // [B][D_INNER][L]
    float* __restrict__ XDBL,          // [B][64][L] fp32 (atomic)
    float* __restrict__ OutB,          // [B][16][L]  (atomic)
    float* __restrict__ OutC) {        // [B][16][L]  (atomic)
  const int ln = blockIdx.x;
  const int sk = blockIdx.y;
  const int b  = blockIdx.z;
  __shared__ ushort_t As[96 * 40];
  __shared__ ushort_t Bs[128 * 34];
  const int tid  = threadIdx.x;
  const int wv   = tid >> 6;
  const int lane = tid & 63;
  const int wr = wv >> 1, wc = wv & 1;
  const int ksel = lane >> 4;
  const int frow = lane & 15;

  const float* Xb = X + (size_t)b * D_INNER * L_SEQ + (size_t)ln * 128;

  f32x4 acc[3][4];
#pragma unroll
  for (int i = 0; i < 3; ++i)
#pragma unroll
    for (int j = 0; j < 4; ++j) acc[i][j] = (f32x4){0.f, 0.f, 0.f, 0.f};

  for (int k0 = 0; k0 < 256; k0 += 32) {
    const int koff = sk * 256 + k0;
    {
      int row = tid >> 2, s = tid & 3;
      bf16x8 v = *(const bf16x8*)(XWb + (size_t)row * D_INNER + koff + s * 8);
      *(bf16x8*)(As + row * 40 + s * 8) = v;
      if (tid < 128) {
        int row2 = 64 + (tid >> 2);
        bf16x8 v2 = *(const bf16x8*)(XWb + (size_t)row2 * D_INNER + koff + s * 8);
        *(bf16x8*)(As + row2 * 40 + s * 8) = v2;
      }
    }
#pragma unroll
    for (int j = 0; j < 2; ++j) {
      int u = tid + 256 * j;
      int n4 = u & 31;
      int kp = u >> 5;
      const float* g0 = Xb + (size_t)(koff + 2 * kp) * L_SEQ + 4 * n4;
      float4 x0 = *(const float4*)g0;
      float4 x1 = *(const float4*)(g0 + L_SEQ);
      float e0[4] = {x0.x, x0.y, x0.z, x0.w};
      float e1[4] = {x1.x, x1.y, x1.z, x1.w};
#pragma unroll
      for (int i = 0; i < 4; ++i) {
        uint_t pk = (uint_t)f2bf(e0[i]) | ((uint_t)f2bf(e1[i]) << 16);
        int n = 4 * n4 + i;
        *(uint_t*)(Bs + n * 34 + 2 * kp) = pk;
      }
    }
    __syncthreads();

    bf16x8 af[3], bfr[4];
#pragma unroll
    for (int mi = 0; mi < 3; ++mi) {
      int row = wr * 48 + mi * 16 + frow;
      af[mi] = *(const bf16x8*)(As + row * 40 + ksel * 8);
    }
#pragma unroll
    for (int ni = 0; ni < 4; ++ni) {
      int n = wc * 64 + ni * 16 + frow;
      const uint_t* p = (const uint_t*)(Bs + n * 34);
      union { uint_t u[4]; bf16x8 v; } fr;
#pragma unroll
      for (int q = 0; q < 4; ++q) fr.u[q] = p[ksel * 4 + q];
      bfr[ni] = fr.v;
    }
#pragma unroll
    for (int mi = 0; mi < 3; ++mi)
#pragma unroll
      for (int ni = 0; ni < 4; ++ni)
        acc[mi][ni] = __builtin_amdgcn_mfma_f32_16x16x32_bf16(af[mi], bfr[ni], acc[mi][ni], 0, 0, 0);
    __syncthreads();
  }

  const int crow0 = (lane >> 4) * 4;
  const int ccol  = lane & 15;
#pragma unroll
  for (int mi = 0; mi < 3; ++mi) {
    int e0 = wr * 48 + mi * 16 + crow0;
    float* base;
    int eoff;
    if (e0 < 64)      { base = XDBL + (size_t)b * 64 * L_SEQ; eoff = e0; }
    else if (e0 < 80) { base = OutB + (size_t)b * D_STATE * L_SEQ; eoff = e0 - 64; }
    else              { base = OutC + (size_t)b * D_STATE * L_SEQ; eoff = e0 - 80; }
#pragma unroll
    for (int ni = 0; ni < 4; ++ni) {
      int l = ln * 128 + wc * 64 + ni * 16 + ccol;
#pragma unroll
      for (int r = 0; r < 4; ++r)
        atomicAdd(base + (size_t)(eoff + r) * L_SEQ + l, acc[mi][ni][r]);
    }
  }
}

// ---------------------------------------------------------------------------
// K4: dt GEMM: DT[b][d][l] = sum_r DW[d][r] * XDBL[b][r][l]; K=64 (fp32)
// ---------------------------------------------------------------------------
__global__ __launch_bounds__(256) void k_dt(const float* __restrict__ DW,
                                            const float* __restrict__ XDBL,
                                            float* __restrict__ DT) {
  const int b = blockIdx.z, bm = blockIdx.y, bn = blockIdx.x;
  __shared__ float As[64][68];
  __shared__ float Bs[64][68];
  const int tid = threadIdx.x;
  const int tx = tid & 15, ty = tid >> 4;
  const int row = tid >> 4;
  const int col = (tid & 15) << 2;
  const float* Bb = XDBL + (size_t)b * DT_RANK * L_SEQ;
#pragma unroll
  for (int q = 0; q < 4; ++q) {
    int r = q * 16 + row;
    float4 av = *(const float4*)(DW + (size_t)(bm * 64 + r) * DT_RANK + col);
    As[col + 0][r] = av.x; As[col + 1][r] = av.y;
    As[col + 2][r] = av.z; As[col + 3][r] = av.w;
    float4 bv = *(const float4*)(Bb + (size_t)r * L_SEQ + bn * 64 + col);
    *(float4*)&Bs[r][col] = bv;
  }
  __syncthreads();
  float acc[4][4] = {};
#pragma unroll 16
  for (int kk = 0; kk < 64; ++kk) {
    float4 a4 = *(const float4*)&As[kk][ty << 2];
    float4 b4 = *(const float4*)&Bs[kk][tx << 2];
    float a[4] = {a4.x, a4.y, a4.z, a4.w};
    float bb[4] = {b4.x, b4.y, b4.z, b4.w};
#pragma unroll
    for (int i = 0; i < 4; ++i)
#pragma unroll
      for (int j = 0; j < 4; ++j) acc[i][j] += a[i] * bb[j];
  }
  float* Cp = DT + (size_t)b * D_INNER * L_SEQ
                 + (size_t)(bm * 64 + (ty << 2)) * L_SEQ + bn * 64 + (tx << 2);
#pragma unroll
  for (int i = 0; i < 4; ++i) {
    float4 v = make_float4(acc[i][0], acc[i][1], acc[i][2], acc[i][3]);
    *(float4*)(Cp + (size_t)i * L_SEQ) = v;
  }
}

// ---------------------------------------------------------------------------
// K5: A = -exp(A_log)
// ---------------------------------------------------------------------------
__global__ __launch_bounds__(256) void k_A(const float* __restrict__ Alog,
                                           float* __restrict__ Aout) {
  int i = blockIdx.x * 256 + threadIdx.x;
  if (i < D_INNER * D_STATE) Aout[i] = -expf(Alog[i]);
}

extern "C" void kernel_launch(void* const* d_in, const int* in_sizes, int n_in,
                              void* d_out, int out_size, void* d_ws, size_t ws_size,
                              hipStream_t stream) {
  const float* hs   = (const float*)d_in[0];
  const float* ipw  = (const float*)d_in[1];
  const float* cw   = (const float*)d_in[2];
  const float* cb   = (const float*)d_in[3];
  const float* xpw  = (const float*)d_in[4];
  const float* dpw  = (const float*)d_in[5];
  const float* alog = (const float*)d_in[6];

  float* out    = (float*)d_out;
  float* dt_out = out + OFF_DT;
  float* a_out  = out + OFF_A;
  float* b_out  = out + OFF_B;
  float* c_out  = out + OFF_C;
  float* x_out  = out + OFF_X;

  // Scratch plan:
  //  - bf16 HS (16.8 MB) + bf16 W-half (4.2 MB) in x region of d_out (dead
  //    after k_inproj; conv overwrites).
  //  - xpre (pre-conv x, fp32, 67 MB) in dt region (overwritten by k_dt).
  //  - d_ws: xdbl fp32 (2 MB) | XWb bf16 (384 KB).
  unsigned short* bfHS = (unsigned short*)x_out;
  unsigned short* bfW  = bfHS + (size_t)B_SZ * L_SEQ * D_MODEL;
  float* xpre = dt_out;
  float* xdbl = (float*)d_ws;
  unsigned short* xwb = (unsigned short*)((char*)d_ws + (size_t)B_SZ * DT_RANK * L_SEQ * 4);

  // One fused prep launch: 3 casts + zero xdbl + zero B|C (contiguous).
  k_prep<<<dim3(N4_TOT / 256), 256, 0, stream>>>(
      (const float4*)hs, (const float4*)ipw, (const float4*)xpw,
      (ushort4*)bfHS, (ushort4*)bfW, (ushort4*)xwb,
      (float4*)xdbl, (float4*)b_out);

  k_inproj_mfma<<<dim3(16, 16, 4), 256, 0, stream>>>(bfW, bfHS, xpre);
  k_conv<<<dim3(B_SZ * D_INNER), 512, 0, stream>>>(xpre, cw, cb, x_out);
  k_xproj_mfma<<<dim3(16, 8, 4), 256, 0, stream>>>(xwb, x_out, xdbl, b_out, c_out);
  k_dt<<<dim3(32, 32, 4), 256, 0, stream>>>(dpw, xdbl, dt_out);
  k_A<<<dim3((D_INNER * D_STATE + 255) / 256), 256, 0, stream>>>(alog, a_out);
}

// Round 5
// 149.401 us; speedup vs baseline: 3.8707x; 1.0534x over previous
//
#include <hip/hip_runtime.h>
#include <hip/hip_bf16.h>
#include <math.h>

#define D_MODEL 1024
#define D_STATE 16
#define D_CONV  4
#define D_INNER 2048
#define DT_RANK 64
#define B_SZ    4
#define L_SEQ   2048

// d_out layout (floats): dt | A | B | C | x
#define OFF_DT 0
#define OFF_A  (B_SZ * D_INNER * L_SEQ)
#define OFF_B  (OFF_A + D_INNER * D_STATE)
#define OFF_C  (OFF_B + B_SZ * D_STATE * L_SEQ)
#define OFF_X  (OFF_C + B_SZ * D_STATE * L_SEQ)

typedef __attribute__((ext_vector_type(8))) short bf16x8;
typedef __attribute__((ext_vector_type(8))) unsigned short us8;
typedef __attribute__((ext_vector_type(4))) float f32x4;
typedef unsigned short ushort_t;
typedef unsigned int uint_t;

static __device__ __forceinline__ ushort_t f2bf(float f) {
  __hip_bfloat16 h = __float2bfloat16(f);
  return *(ushort_t*)&h;
}
static __device__ __forceinline__ float bf2f(ushort_t u) {
  union { uint_t u; float f; } c;
  c.u = ((uint_t)u) << 16;
  return c.f;
}

// ---------------------------------------------------------------------------
// K0: fused prep — bf16 casts (hs, in_proj x-half, x_proj_w), zero split-K
// targets (xdbl, B|C), and A = -exp(A_log). One launch.
// ---------------------------------------------------------------------------
#define N4_HS   (B_SZ * L_SEQ * D_MODEL / 4)                 // 2097152
#define N4_W    (D_INNER * D_MODEL / 4)                      // 524288
#define N4_XW   ((DT_RANK + 2 * D_STATE) * D_INNER / 4)      // 49152
#define N4_Z0   (B_SZ * DT_RANK * L_SEQ / 4)                 // 131072 (xdbl)
#define N4_Z1   (2 * B_SZ * D_STATE * L_SEQ / 4)             // 65536  (B|C)
#define N4_A    (D_INNER * D_STATE / 4)                      // 8192   (A)
#define N4_TOT  (N4_HS + N4_W + N4_XW + N4_Z0 + N4_Z1 + N4_A)

__global__ __launch_bounds__(256) void k_prep(
    const float4* __restrict__ hs, const float4* __restrict__ ipw,
    const float4* __restrict__ xpw, const float4* __restrict__ alog,
    ushort4* __restrict__ bfHS, ushort4* __restrict__ bfW,
    ushort4* __restrict__ xwb,
    float4* __restrict__ z0, float4* __restrict__ z1,
    float4* __restrict__ aout) {
  int i = blockIdx.x * 256 + threadIdx.x;
  if (i < N4_HS) {
    float4 v = hs[i];
    ushort4 o; o.x = f2bf(v.x); o.y = f2bf(v.y); o.z = f2bf(v.z); o.w = f2bf(v.w);
    bfHS[i] = o;
    return;
  }
  i -= N4_HS;
  if (i < N4_W) {
    float4 v = ipw[i];
    ushort4 o; o.x = f2bf(v.x); o.y = f2bf(v.y); o.z = f2bf(v.z); o.w = f2bf(v.w);
    bfW[i] = o;
    return;
  }
  i -= N4_W;
  if (i < N4_XW) {
    float4 v = xpw[i];
    ushort4 o; o.x = f2bf(v.x); o.y = f2bf(v.y); o.z = f2bf(v.z); o.w = f2bf(v.w);
    xwb[i] = o;
    return;
  }
  i -= N4_XW;
  if (i < N4_Z0) { z0[i] = (float4){0.f, 0.f, 0.f, 0.f}; return; }
  i -= N4_Z0;
  if (i < N4_Z1) { z1[i] = (float4){0.f, 0.f, 0.f, 0.f}; return; }
  i -= N4_Z1;
  if (i < N4_A) {
    float4 v = alog[i];
    float4 o;
    o.x = -expf(v.x); o.y = -expf(v.y); o.z = -expf(v.z); o.w = -expf(v.w);
    aout[i] = o;
  }
}

// ---------------------------------------------------------------------------
// K1: in_proj (x half) via bf16 MFMA, XCD-swizzled block mapping.
// C[b][d][l] = sum_k W[d][k] * HS[b][l][k]   (NT GEMM, both K-major)
// Output xpre stored as bf16 (pure intermediate; halves write traffic).
// ---------------------------------------------------------------------------
__global__ __launch_bounds__(256) void k_inproj_mfma(
    const ushort_t* __restrict__ Wb,   // [D_INNER][D_MODEL] bf16
    const ushort_t* __restrict__ HSb,  // [B][L][D_MODEL] bf16
    ushort_t* __restrict__ Cout) {     // [B][D_INNER][L] bf16
  // XCD-aware bijective swizzle: nwg = 16*16*4 = 1024, 1024 % 8 == 0.
  const int flat = blockIdx.x + 16 * blockIdx.y + 256 * blockIdx.z;
  const int swz  = (flat & 7) * 128 + (flat >> 3);
  const int bn = swz & 15;
  const int bm = (swz >> 4) & 15;
  const int b  = swz >> 8;

  __shared__ ushort_t As[128 * 32];
  __shared__ ushort_t Bs[128 * 32];
  const int tid  = threadIdx.x;
  const int wv   = tid >> 6;
  const int lane = tid & 63;
  const int wr = wv >> 1, wc = wv & 1;

  const int srow = tid >> 2;
  const int ss   = tid & 3;

  const ushort_t* Ag = Wb + (size_t)(bm * 128) * D_MODEL;
  const ushort_t* Bg = HSb + (size_t)b * L_SEQ * D_MODEL
                           + (size_t)(bn * 128) * D_MODEL;

  f32x4 acc[4][4];
#pragma unroll
  for (int i = 0; i < 4; ++i)
#pragma unroll
    for (int j = 0; j < 4; ++j) acc[i][j] = (f32x4){0.f, 0.f, 0.f, 0.f};

  const int ksel = lane >> 4;
  const int frow = lane & 15;

  for (int k0 = 0; k0 < D_MODEL; k0 += 32) {
#pragma unroll
    for (int q = 0; q < 2; ++q) {
      int row = q * 64 + srow;
      int xs  = ss ^ ((row >> 1) & 3);
      const ushort_t* ga = Ag + (size_t)row * D_MODEL + k0 + xs * 8;
      const ushort_t* gb = Bg + (size_t)row * D_MODEL + k0 + xs * 8;
      ushort_t* la = As + (q * 256 + wv * 64) * 8;
      ushort_t* lb = Bs + (q * 256 + wv * 64) * 8;
      __builtin_amdgcn_global_load_lds((const __attribute__((address_space(1))) void*)ga,
                                       (__attribute__((address_space(3))) void*)la, 16, 0, 0);
      __builtin_amdgcn_global_load_lds((const __attribute__((address_space(1))) void*)gb,
                                       (__attribute__((address_space(3))) void*)lb, 16, 0, 0);
    }
    __syncthreads();

    bf16x8 af[4], bfr[4];
#pragma unroll
    for (int m = 0; m < 4; ++m) {
      int row = wr * 64 + m * 16 + frow;
      af[m] = *(const bf16x8*)(As + (row * 4 + (ksel ^ ((row >> 1) & 3))) * 8);
    }
#pragma unroll
    for (int n = 0; n < 4; ++n) {
      int row = wc * 64 + n * 16 + frow;
      bfr[n] = *(const bf16x8*)(Bs + (row * 4 + (ksel ^ ((row >> 1) & 3))) * 8);
    }
#pragma unroll
    for (int m = 0; m < 4; ++m)
#pragma unroll
      for (int n = 0; n < 4; ++n)
        acc[m][n] = __builtin_amdgcn_mfma_f32_16x16x32_bf16(af[m], bfr[n], acc[m][n], 0, 0, 0);
    __syncthreads();
  }

  const int crow0 = (lane >> 4) * 4;
  const int ccol  = lane & 15;
  ushort_t* Cb = Cout + (size_t)b * D_INNER * L_SEQ;
#pragma unroll
  for (int m = 0; m < 4; ++m) {
    int gr0 = bm * 128 + wr * 64 + m * 16 + crow0;
#pragma unroll
    for (int n = 0; n < 4; ++n) {
      int gc = bn * 128 + wc * 64 + n * 16 + ccol;
#pragma unroll
      for (int i = 0; i < 4; ++i)
        Cb[(size_t)(gr0 + i) * L_SEQ + gc] = f2bf(acc[m][n][i]);
    }
  }
}

// ---------------------------------------------------------------------------
// K2: causal depthwise conv4 + bias + SiLU, bf16 input, fp32 output.
// One block per (b,d) row; 256 threads x 8 elems.
// ---------------------------------------------------------------------------
__global__ __launch_bounds__(256) void k_conv(const ushort_t* __restrict__ Xp,
                                              const float* __restrict__ CW,
                                              const float* __restrict__ CB,
                                              float* __restrict__ Xo) {
  const int bd = blockIdx.x;            // b*D_INNER + d
  const int d  = bd & (D_INNER - 1);
  const ushort_t* row = Xp + (size_t)bd * L_SEQ;
  float* orow = Xo + (size_t)bd * L_SEQ;
  const float w0 = CW[d * 4 + 0], w1 = CW[d * 4 + 1];
  const float w2 = CW[d * 4 + 2], w3 = CW[d * 4 + 3];
  const float bias = CB[d];
  const int l0 = threadIdx.x << 3;

  us8 cur = *(const us8*)(row + l0);
  float e[11];
  e[0] = 0.f; e[1] = 0.f; e[2] = 0.f;
  if (l0 >= 4) {
    ushort4 pv = *(const ushort4*)(row + l0 - 4);
    e[0] = bf2f(pv.y); e[1] = bf2f(pv.z); e[2] = bf2f(pv.w);
  }
#pragma unroll
  for (int j = 0; j < 8; ++j) e[3 + j] = bf2f(cur[j]);

  float4 o0, o1;
  float* op = &o0.x;
#pragma unroll
  for (int j = 0; j < 8; ++j) {
    float v = w0 * e[j] + w1 * e[j + 1] + w2 * e[j + 2] + w3 * e[j + 3] + bias;
    float s = v / (1.f + expf(-v));
    if (j < 4) (&o0.x)[j] = s; else (&o1.x)[j - 4] = s;
  }
  (void)op;
  *(float4*)(orow + l0)     = o0;
  *(float4*)(orow + l0 + 4) = o1;
}

// ---------------------------------------------------------------------------
// K3: x_proj via bf16 MFMA, split-K, in-kernel B transpose, atomic epilogue.
// ---------------------------------------------------------------------------
__global__ __launch_bounds__(256) void k_xproj_mfma(
    const ushort_t* __restrict__ XWb,  // [96][2048] bf16
    const float* __restrict__ X,       // [B][D_INNER][L]
    float* __restrict__ XDBL,          // [B][64][L] fp32 (atomic)
    float* __restrict__ OutB,          // [B][16][L]  (atomic)
    float* __restrict__ OutC) {        // [B][16][L]  (atomic)
  const int ln = blockIdx.x;
  const int sk = blockIdx.y;
  const int b  = blockIdx.z;
  __shared__ ushort_t As[96 * 40];
  __shared__ ushort_t Bs[128 * 34];
  const int tid  = threadIdx.x;
  const int wv   = tid >> 6;
  const int lane = tid & 63;
  const int wr = wv >> 1, wc = wv & 1;
  const int ksel = lane >> 4;
  const int frow = lane & 15;

  const float* Xb = X + (size_t)b * D_INNER * L_SEQ + (size_t)ln * 128;

  f32x4 acc[3][4];
#pragma unroll
  for (int i = 0; i < 3; ++i)
#pragma unroll
    for (int j = 0; j < 4; ++j) acc[i][j] = (f32x4){0.f, 0.f, 0.f, 0.f};

  for (int k0 = 0; k0 < 256; k0 += 32) {
    const int koff = sk * 256 + k0;
    {
      int row = tid >> 2, s = tid & 3;
      bf16x8 v = *(const bf16x8*)(XWb + (size_t)row * D_INNER + koff + s * 8);
      *(bf16x8*)(As + row * 40 + s * 8) = v;
      if (tid < 128) {
        int row2 = 64 + (tid >> 2);
        bf16x8 v2 = *(const bf16x8*)(XWb + (size_t)row2 * D_INNER + koff + s * 8);
        *(bf16x8*)(As + row2 * 40 + s * 8) = v2;
      }
    }
#pragma unroll
    for (int j = 0; j < 2; ++j) {
      int u = tid + 256 * j;
      int n4 = u & 31;
      int kp = u >> 5;
      const float* g0 = Xb + (size_t)(koff + 2 * kp) * L_SEQ + 4 * n4;
      float4 x0 = *(const float4*)g0;
      float4 x1 = *(const float4*)(g0 + L_SEQ);
      float e0[4] = {x0.x, x0.y, x0.z, x0.w};
      float e1[4] = {x1.x, x1.y, x1.z, x1.w};
#pragma unroll
      for (int i = 0; i < 4; ++i) {
        uint_t pk = (uint_t)f2bf(e0[i]) | ((uint_t)f2bf(e1[i]) << 16);
        int n = 4 * n4 + i;
        *(uint_t*)(Bs + n * 34 + 2 * kp) = pk;
      }
    }
    __syncthreads();

    bf16x8 af[3], bfr[4];
#pragma unroll
    for (int mi = 0; mi < 3; ++mi) {
      int row = wr * 48 + mi * 16 + frow;
      af[mi] = *(const bf16x8*)(As + row * 40 + ksel * 8);
    }
#pragma unroll
    for (int ni = 0; ni < 4; ++ni) {
      int n = wc * 64 + ni * 16 + frow;
      const uint_t* p = (const uint_t*)(Bs + n * 34);
      union { uint_t u[4]; bf16x8 v; } fr;
#pragma unroll
      for (int q = 0; q < 4; ++q) fr.u[q] = p[ksel * 4 + q];
      bfr[ni] = fr.v;
    }
#pragma unroll
    for (int mi = 0; mi < 3; ++mi)
#pragma unroll
      for (int ni = 0; ni < 4; ++ni)
        acc[mi][ni] = __builtin_amdgcn_mfma_f32_16x16x32_bf16(af[mi], bfr[ni], acc[mi][ni], 0, 0, 0);
    __syncthreads();
  }

  const int crow0 = (lane >> 4) * 4;
  const int ccol  = lane & 15;
#pragma unroll
  for (int mi = 0; mi < 3; ++mi) {
    int e0 = wr * 48 + mi * 16 + crow0;
    float* base;
    int eoff;
    if (e0 < 64)      { base = XDBL + (size_t)b * 64 * L_SEQ; eoff = e0; }
    else if (e0 < 80) { base = OutB + (size_t)b * D_STATE * L_SEQ; eoff = e0 - 64; }
    else              { base = OutC + (size_t)b * D_STATE * L_SEQ; eoff = e0 - 80; }
#pragma unroll
    for (int ni = 0; ni < 4; ++ni) {
      int l = ln * 128 + wc * 64 + ni * 16 + ccol;
#pragma unroll
      for (int r = 0; r < 4; ++r)
        atomicAdd(base + (size_t)(eoff + r) * L_SEQ + l, acc[mi][ni][r]);
    }
  }
}

// ---------------------------------------------------------------------------
// K4: dt GEMM: DT[b][d][l] = sum_r DW[d][r] * XDBL[b][r][l]; K=64 (fp32)
// ---------------------------------------------------------------------------
__global__ __launch_bounds__(256) void k_dt(const float* __restrict__ DW,
                                            const float* __restrict__ XDBL,
                                            float* __restrict__ DT) {
  const int b = blockIdx.z, bm = blockIdx.y, bn = blockIdx.x;
  __shared__ float As[64][68];
  __shared__ float Bs[64][68];
  const int tid = threadIdx.x;
  const int tx = tid & 15, ty = tid >> 4;
  const int row = tid >> 4;
  const int col = (tid & 15) << 2;
  const float* Bb = XDBL + (size_t)b * DT_RANK * L_SEQ;
#pragma unroll
  for (int q = 0; q < 4; ++q) {
    int r = q * 16 + row;
    float4 av = *(const float4*)(DW + (size_t)(bm * 64 + r) * DT_RANK + col);
    As[col + 0][r] = av.x; As[col + 1][r] = av.y;
    As[col + 2][r] = av.z; As[col + 3][r] = av.w;
    float4 bv = *(const float4*)(Bb + (size_t)r * L_SEQ + bn * 64 + col);
    *(float4*)&Bs[r][col] = bv;
  }
  __syncthreads();
  float acc[4][4] = {};
#pragma unroll 16
  for (int kk = 0; kk < 64; ++kk) {
    float4 a4 = *(const float4*)&As[kk][ty << 2];
    float4 b4 = *(const float4*)&Bs[kk][tx << 2];
    float a[4] = {a4.x, a4.y, a4.z, a4.w};
    float bb[4] = {b4.x, b4.y, b4.z, b4.w};
#pragma unroll
    for (int i = 0; i < 4; ++i)
#pragma unroll
      for (int j = 0; j < 4; ++j) acc[i][j] += a[i] * bb[j];
  }
  float* Cp = DT + (size_t)b * D_INNER * L_SEQ
                 + (size_t)(bm * 64 + (ty << 2)) * L_SEQ + bn * 64 + (tx << 2);
#pragma unroll
  for (int i = 0; i < 4; ++i) {
    float4 v = make_float4(acc[i][0], acc[i][1], acc[i][2], acc[i][3]);
    *(float4*)(Cp + (size_t)i * L_SEQ) = v;
  }
}

extern "C" void kernel_launch(void* const* d_in, const int* in_sizes, int n_in,
                              void* d_out, int out_size, void* d_ws, size_t ws_size,
                              hipStream_t stream) {
  const float* hs   = (const float*)d_in[0];
  const float* ipw  = (const float*)d_in[1];
  const float* cw   = (const float*)d_in[2];
  const float* cb   = (const float*)d_in[3];
  const float* xpw  = (const float*)d_in[4];
  const float* dpw  = (const float*)d_in[5];
  const float* alog = (const float*)d_in[6];

  float* out    = (float*)d_out;
  float* dt_out = out + OFF_DT;
  float* a_out  = out + OFF_A;
  float* b_out  = out + OFF_B;
  float* c_out  = out + OFF_C;
  float* x_out  = out + OFF_X;

  // Scratch plan:
  //  - bf16 HS (16.8 MB) + bf16 W-half (4.2 MB) in x region of d_out (dead
  //    after k_inproj; conv overwrites).
  //  - xpre (pre-conv x, bf16, 33.5 MB) in dt region (overwritten by k_dt).
  //  - d_ws: xdbl fp32 (2 MB) | XWb bf16 (384 KB).
  unsigned short* bfHS = (unsigned short*)x_out;
  unsigned short* bfW  = bfHS + (size_t)B_SZ * L_SEQ * D_MODEL;
  unsigned short* xpre = (unsigned short*)dt_out;
  float* xdbl = (float*)d_ws;
  unsigned short* xwb = (unsigned short*)((char*)d_ws + (size_t)B_SZ * DT_RANK * L_SEQ * 4);

  // One fused prep launch: 3 casts + zero xdbl + zero B|C + A = -exp(A_log).
  k_prep<<<dim3(N4_TOT / 256), 256, 0, stream>>>(
      (const float4*)hs, (const float4*)ipw, (const float4*)xpw,
      (const float4*)alog,
      (ushort4*)bfHS, (ushort4*)bfW, (ushort4*)xwb,
      (float4*)xdbl, (float4*)b_out, (float4*)a_out);

  k_inproj_mfma<<<dim3(16, 16, 4), 256, 0, stream>>>(bfW, bfHS, xpre);
  k_conv<<<dim3(B_SZ * D_INNER), 256, 0, stream>>>(xpre, cw, cb, x_out);
  k_xproj_mfma<<<dim3(16, 8, 4), 256, 0, stream>>>(xwb, x_out, xdbl, b_out, c_out);
  k_dt<<<dim3(32, 32, 4), 256, 0, stream>>>(dpw, xdbl, dt_out);
}

// Round 6
// 132.985 us; speedup vs baseline: 4.3485x; 1.1234x over previous
//
#include <hip/hip_runtime.h>
#include <hip/hip_bf16.h>
#include <math.h>

#define D_MODEL 1024
#define D_STATE 16
#define D_CONV  4
#define D_INNER 2048
#define DT_RANK 64
#define B_SZ    4
#define L_SEQ   2048

// d_out layout (floats): dt | A | B | C | x
#define OFF_DT 0
#define OFF_A  (B_SZ * D_INNER * L_SEQ)
#define OFF_B  (OFF_A + D_INNER * D_STATE)
#define OFF_C  (OFF_B + B_SZ * D_STATE * L_SEQ)
#define OFF_X  (OFF_C + B_SZ * D_STATE * L_SEQ)

typedef __attribute__((ext_vector_type(8))) short bf16x8;
typedef __attribute__((ext_vector_type(8))) unsigned short us8;
typedef __attribute__((ext_vector_type(4))) float f32x4;
typedef unsigned short ushort_t;
typedef unsigned int uint_t;

static __device__ __forceinline__ ushort_t f2bf(float f) {
  __hip_bfloat16 h = __float2bfloat16(f);
  return *(ushort_t*)&h;
}
static __device__ __forceinline__ float bf2f(ushort_t u) {
  union { uint_t u; float f; } c;
  c.u = ((uint_t)u) << 16;
  return c.f;
}

// ---------------------------------------------------------------------------
// K0: fused prep — bf16 casts (hs, in_proj x-half, x_proj_w, dt_proj_w),
// zero split-K targets (xdbl, B|C), and A = -exp(A_log). One launch.
// ---------------------------------------------------------------------------
#define N4_HS   (B_SZ * L_SEQ * D_MODEL / 4)                 // 2097152
#define N4_W    (D_INNER * D_MODEL / 4)                      // 524288
#define N4_XW   ((DT_RANK + 2 * D_STATE) * D_INNER / 4)      // 49152
#define N4_DW   (D_INNER * DT_RANK / 4)                      // 32768
#define N4_Z0   (B_SZ * DT_RANK * L_SEQ / 4)                 // 131072 (xdbl)
#define N4_Z1   (2 * B_SZ * D_STATE * L_SEQ / 4)             // 65536  (B|C)
#define N4_A    (D_INNER * D_STATE / 4)                      // 8192   (A)
#define N4_TOT  (N4_HS + N4_W + N4_XW + N4_DW + N4_Z0 + N4_Z1 + N4_A)

__global__ __launch_bounds__(256) void k_prep(
    const float4* __restrict__ hs, const float4* __restrict__ ipw,
    const float4* __restrict__ xpw, const float4* __restrict__ dpw,
    const float4* __restrict__ alog,
    ushort4* __restrict__ bfHS, ushort4* __restrict__ bfW,
    ushort4* __restrict__ xwb, ushort4* __restrict__ dwb,
    float4* __restrict__ z0, float4* __restrict__ z1,
    float4* __restrict__ aout) {
  int i = blockIdx.x * 256 + threadIdx.x;
  if (i < N4_HS) {
    float4 v = hs[i];
    ushort4 o; o.x = f2bf(v.x); o.y = f2bf(v.y); o.z = f2bf(v.z); o.w = f2bf(v.w);
    bfHS[i] = o;
    return;
  }
  i -= N4_HS;
  if (i < N4_W) {
    float4 v = ipw[i];
    ushort4 o; o.x = f2bf(v.x); o.y = f2bf(v.y); o.z = f2bf(v.z); o.w = f2bf(v.w);
    bfW[i] = o;
    return;
  }
  i -= N4_W;
  if (i < N4_XW) {
    float4 v = xpw[i];
    ushort4 o; o.x = f2bf(v.x); o.y = f2bf(v.y); o.z = f2bf(v.z); o.w = f2bf(v.w);
    xwb[i] = o;
    return;
  }
  i -= N4_XW;
  if (i < N4_DW) {
    float4 v = dpw[i];
    ushort4 o; o.x = f2bf(v.x); o.y = f2bf(v.y); o.z = f2bf(v.z); o.w = f2bf(v.w);
    dwb[i] = o;
    return;
  }
  i -= N4_DW;
  if (i < N4_Z0) { z0[i] = (float4){0.f, 0.f, 0.f, 0.f}; return; }
  i -= N4_Z0;
  if (i < N4_Z1) { z1[i] = (float4){0.f, 0.f, 0.f, 0.f}; return; }
  i -= N4_Z1;
  if (i < N4_A) {
    float4 v = alog[i];
    float4 o;
    o.x = -expf(v.x); o.y = -expf(v.y); o.z = -expf(v.z); o.w = -expf(v.w);
    aout[i] = o;
  }
}

// ---------------------------------------------------------------------------
// K1: in_proj (x half) via bf16 MFMA, XCD-swizzled block mapping.
// C[b][d][l] = sum_k W[d][k] * HS[b][l][k]   (NT GEMM, both K-major)
// Output xpre stored as bf16 (pure intermediate; halves write traffic).
// ---------------------------------------------------------------------------
__global__ __launch_bounds__(256) void k_inproj_mfma(
    const ushort_t* __restrict__ Wb,   // [D_INNER][D_MODEL] bf16
    const ushort_t* __restrict__ HSb,  // [B][L][D_MODEL] bf16
    ushort_t* __restrict__ Cout) {     // [B][D_INNER][L] bf16
  // XCD-aware bijective swizzle: nwg = 16*16*4 = 1024, 1024 % 8 == 0.
  const int flat = blockIdx.x + 16 * blockIdx.y + 256 * blockIdx.z;
  const int swz  = (flat & 7) * 128 + (flat >> 3);
  const int bn = swz & 15;
  const int bm = (swz >> 4) & 15;
  const int b  = swz >> 8;

  __shared__ ushort_t As[128 * 32];
  __shared__ ushort_t Bs[128 * 32];
  const int tid  = threadIdx.x;
  const int wv   = tid >> 6;
  const int lane = tid & 63;
  const int wr = wv >> 1, wc = wv & 1;

  const int srow = tid >> 2;
  const int ss   = tid & 3;

  const ushort_t* Ag = Wb + (size_t)(bm * 128) * D_MODEL;
  const ushort_t* Bg = HSb + (size_t)b * L_SEQ * D_MODEL
                           + (size_t)(bn * 128) * D_MODEL;

  f32x4 acc[4][4];
#pragma unroll
  for (int i = 0; i < 4; ++i)
#pragma unroll
    for (int j = 0; j < 4; ++j) acc[i][j] = (f32x4){0.f, 0.f, 0.f, 0.f};

  const int ksel = lane >> 4;
  const int frow = lane & 15;

  for (int k0 = 0; k0 < D_MODEL; k0 += 32) {
#pragma unroll
    for (int q = 0; q < 2; ++q) {
      int row = q * 64 + srow;
      int xs  = ss ^ ((row >> 1) & 3);
      const ushort_t* ga = Ag + (size_t)row * D_MODEL + k0 + xs * 8;
      const ushort_t* gb = Bg + (size_t)row * D_MODEL + k0 + xs * 8;
      ushort_t* la = As + (q * 256 + wv * 64) * 8;
      ushort_t* lb = Bs + (q * 256 + wv * 64) * 8;
      __builtin_amdgcn_global_load_lds((const __attribute__((address_space(1))) void*)ga,
                                       (__attribute__((address_space(3))) void*)la, 16, 0, 0);
      __builtin_amdgcn_global_load_lds((const __attribute__((address_space(1))) void*)gb,
                                       (__attribute__((address_space(3))) void*)lb, 16, 0, 0);
    }
    __syncthreads();

    bf16x8 af[4], bfr[4];
#pragma unroll
    for (int m = 0; m < 4; ++m) {
      int row = wr * 64 + m * 16 + frow;
      af[m] = *(const bf16x8*)(As + (row * 4 + (ksel ^ ((row >> 1) & 3))) * 8);
    }
#pragma unroll
    for (int n = 0; n < 4; ++n) {
      int row = wc * 64 + n * 16 + frow;
      bfr[n] = *(const bf16x8*)(Bs + (row * 4 + (ksel ^ ((row >> 1) & 3))) * 8);
    }
#pragma unroll
    for (int m = 0; m < 4; ++m)
#pragma unroll
      for (int n = 0; n < 4; ++n)
        acc[m][n] = __builtin_amdgcn_mfma_f32_16x16x32_bf16(af[m], bfr[n], acc[m][n], 0, 0, 0);
    __syncthreads();
  }

  const int crow0 = (lane >> 4) * 4;
  const int ccol  = lane & 15;
  ushort_t* Cb = Cout + (size_t)b * D_INNER * L_SEQ;
#pragma unroll
  for (int m = 0; m < 4; ++m) {
    int gr0 = bm * 128 + wr * 64 + m * 16 + crow0;
#pragma unroll
    for (int n = 0; n < 4; ++n) {
      int gc = bn * 128 + wc * 64 + n * 16 + ccol;
#pragma unroll
      for (int i = 0; i < 4; ++i)
        Cb[(size_t)(gr0 + i) * L_SEQ + gc] = f2bf(acc[m][n][i]);
    }
  }
}

// ---------------------------------------------------------------------------
// K3: x_proj via bf16 MFMA, split-K, with conv4+SiLU fused into B-staging.
// Reads xpre (bf16 pre-conv), computes conv+SiLU in registers, writes the
// x output (fp32) as a side effect, packs bf16 B-fragments for the GEMM.
// C[b][e][l] = sum_d XW[e][d] * silu(conv(xpre))[b][d][l]
// Epilogue: fp32 atomicAdd into xdbl / B_mat / C_mat (zeroed in prep).
// ---------------------------------------------------------------------------
__global__ __launch_bounds__(256) void k_xproj_fused(
    const ushort_t* __restrict__ XWb,  // [96][2048] bf16
    const ushort_t* __restrict__ Xpre, // [B][D_INNER][L] bf16 (pre-conv)
    const float* __restrict__ CW,      // [D_INNER][4] conv weights
    const float* __restrict__ CB,      // [D_INNER] conv bias
    float* __restrict__ Xout,          // [B][D_INNER][L] fp32 (post conv+silu)
    float* __restrict__ XDBL,          // [B][64][L] fp32 (atomic)
    float* __restrict__ OutB,          // [B][16][L]  (atomic)
    float* __restrict__ OutC) {        // [B][16][L]  (atomic)
  const int ln = blockIdx.x;   // 0..15
  const int sk = blockIdx.y;   // 0..7
  const int b  = blockIdx.z;
  __shared__ ushort_t As[96 * 40];
  __shared__ ushort_t Bs[128 * 34];
  const int tid  = threadIdx.x;
  const int wv   = tid >> 6;
  const int lane = tid & 63;
  const int wr = wv >> 1, wc = wv & 1;
  const int ksel = lane >> 4;
  const int frow = lane & 15;

  f32x4 acc[3][4];
#pragma unroll
  for (int i = 0; i < 3; ++i)
#pragma unroll
    for (int j = 0; j < 4; ++j) acc[i][j] = (f32x4){0.f, 0.f, 0.f, 0.f};

  for (int k0 = 0; k0 < 256; k0 += 32) {
    const int koff = sk * 256 + k0;
    // ---- stage A tile [96][32] ----
    {
      int row = tid >> 2, s = tid & 3;
      bf16x8 v = *(const bf16x8*)(XWb + (size_t)row * D_INNER + koff + s * 8);
      *(bf16x8*)(As + row * 40 + s * 8) = v;
      if (tid < 128) {
        int row2 = 64 + (tid >> 2);
        bf16x8 v2 = *(const bf16x8*)(XWb + (size_t)row2 * D_INNER + koff + s * 8);
        *(bf16x8*)(As + row2 * 40 + s * 8) = v2;
      }
    }
    // ---- stage B tile: conv+silu from xpre, write x, pack bf16 ----
#pragma unroll
    for (int j = 0; j < 2; ++j) {
      int u = tid + 256 * j;
      int n4 = u & 31;           // l-quad within tile
      int kp = u >> 5;           // d-pair 0..15
      int l0 = ln * 128 + 4 * n4;
      float sv[2][4];
#pragma unroll
      for (int r = 0; r < 2; ++r) {
        int d = koff + 2 * kp + r;
        const ushort_t* row = Xpre + ((size_t)b * D_INNER + d) * L_SEQ;
        ushort4 cur = *(const ushort4*)(row + l0);
        float em3 = 0.f, em2 = 0.f, em1 = 0.f;
        if (l0 >= 4) {
          ushort4 pv = *(const ushort4*)(row + l0 - 4);
          em3 = bf2f(pv.y); em2 = bf2f(pv.z); em1 = bf2f(pv.w);
        }
        float ee[7] = {em3, em2, em1, bf2f(cur.x), bf2f(cur.y), bf2f(cur.z), bf2f(cur.w)};
        float4 w = *(const float4*)(CW + d * 4);
        float bias = CB[d];
#pragma unroll
        for (int i = 0; i < 4; ++i) {
          float v = w.x * ee[i] + w.y * ee[i + 1] + w.z * ee[i + 2] + w.w * ee[i + 3] + bias;
          sv[r][i] = v / (1.f + expf(-v));
        }
        *(float4*)(Xout + ((size_t)b * D_INNER + d) * L_SEQ + l0) =
            make_float4(sv[r][0], sv[r][1], sv[r][2], sv[r][3]);
      }
#pragma unroll
      for (int i = 0; i < 4; ++i) {
        uint_t pk = (uint_t)f2bf(sv[0][i]) | ((uint_t)f2bf(sv[1][i]) << 16);
        *(uint_t*)(Bs + (4 * n4 + i) * 34 + 2 * kp) = pk;
      }
    }
    __syncthreads();

    // ---- fragments ----
    bf16x8 af[3], bfr[4];
#pragma unroll
    for (int mi = 0; mi < 3; ++mi) {
      int row = wr * 48 + mi * 16 + frow;
      af[mi] = *(const bf16x8*)(As + row * 40 + ksel * 8);
    }
#pragma unroll
    for (int ni = 0; ni < 4; ++ni) {
      int n = wc * 64 + ni * 16 + frow;
      const uint_t* p = (const uint_t*)(Bs + n * 34);
      union { uint_t u[4]; bf16x8 v; } fr;
#pragma unroll
      for (int q = 0; q < 4; ++q) fr.u[q] = p[ksel * 4 + q];
      bfr[ni] = fr.v;
    }
#pragma unroll
    for (int mi = 0; mi < 3; ++mi)
#pragma unroll
      for (int ni = 0; ni < 4; ++ni)
        acc[mi][ni] = __builtin_amdgcn_mfma_f32_16x16x32_bf16(af[mi], bfr[ni], acc[mi][ni], 0, 0, 0);
    __syncthreads();
  }

  // ---- epilogue: atomic accumulate ----
  const int crow0 = (lane >> 4) * 4;
  const int ccol  = lane & 15;
#pragma unroll
  for (int mi = 0; mi < 3; ++mi) {
    int e0 = wr * 48 + mi * 16 + crow0;
    float* base;
    int eoff;
    if (e0 < 64)      { base = XDBL + (size_t)b * 64 * L_SEQ; eoff = e0; }
    else if (e0 < 80) { base = OutB + (size_t)b * D_STATE * L_SEQ; eoff = e0 - 64; }
    else              { base = OutC + (size_t)b * D_STATE * L_SEQ; eoff = e0 - 80; }
#pragma unroll
    for (int ni = 0; ni < 4; ++ni) {
      int l = ln * 128 + wc * 64 + ni * 16 + ccol;
#pragma unroll
      for (int r = 0; r < 4; ++r)
        atomicAdd(base + (size_t)(eoff + r) * L_SEQ + l, acc[mi][ni][r]);
    }
  }
}

// ---------------------------------------------------------------------------
// K4: dt GEMM via bf16 MFMA. DT[b][d][l] = sum_r DW[d][r] * XDBL[b][r][l].
// K=64 single-stage; 128x128 tile; 4 waves (2x2); write-bound epilogue.
// ---------------------------------------------------------------------------
__global__ __launch_bounds__(256) void k_dt_mfma(
    const ushort_t* __restrict__ DWb,  // [D_INNER][64] bf16
    const float* __restrict__ XDBL,    // [B][64][L] fp32
    float* __restrict__ DT) {          // [B][D_INNER][L] fp32
  const int ln = blockIdx.x;   // 0..15 (l tile)
  const int dm = blockIdx.y;   // 0..15 (d tile)
  const int b  = blockIdx.z;
  __shared__ ushort_t As[128 * 72];    // [d][r], pad 72 (2-way reads)
  __shared__ ushort_t Bs[128 * 68];    // [l][r], pad 68 (conflict-free reads)
  const int tid  = threadIdx.x;
  const int wv   = tid >> 6;
  const int lane = tid & 63;
  const int wr = wv >> 1, wc = wv & 1;
  const int ksel = lane >> 4;
  const int frow = lane & 15;

  // stage A: DWb rows dm*128..+127, 64 r each (8 slots of 8 bf16)
#pragma unroll
  for (int q = 0; q < 4; ++q) {
    int u = tid + 256 * q;
    int row = u >> 3, s = u & 7;
    *(bf16x8*)(As + row * 72 + s * 8) =
        *(const bf16x8*)(DWb + (size_t)(dm * 128 + row) * DT_RANK + s * 8);
  }
  // stage B: transpose XDBL[r][l] -> Bs[l][r] (bf16 pairs)
#pragma unroll
  for (int q = 0; q < 4; ++q) {
    int u = tid + 256 * q;
    int n4 = u & 31;           // l-quad
    int kp = u >> 5;           // r-pair 0..31
    const float* g = XDBL + ((size_t)b * DT_RANK + 2 * kp) * L_SEQ + ln * 128 + 4 * n4;
    float4 x0 = *(const float4*)g;
    float4 x1 = *(const float4*)(g + L_SEQ);
    float e0[4] = {x0.x, x0.y, x0.z, x0.w};
    float e1[4] = {x1.x, x1.y, x1.z, x1.w};
#pragma unroll
    for (int i = 0; i < 4; ++i) {
      uint_t pk = (uint_t)f2bf(e0[i]) | ((uint_t)f2bf(e1[i]) << 16);
      *(uint_t*)(Bs + (4 * n4 + i) * 68 + 2 * kp) = pk;
    }
  }
  __syncthreads();

  f32x4 acc[4][4];
#pragma unroll
  for (int i = 0; i < 4; ++i)
#pragma unroll
    for (int j = 0; j < 4; ++j) acc[i][j] = (f32x4){0.f, 0.f, 0.f, 0.f};

#pragma unroll
  for (int ks = 0; ks < 2; ++ks) {
    bf16x8 af[4], bfr[4];
#pragma unroll
    for (int m = 0; m < 4; ++m) {
      int row = wr * 64 + m * 16 + frow;
      af[m] = *(const bf16x8*)(As + row * 72 + ks * 32 + ksel * 8);
    }
#pragma unroll
    for (int n = 0; n < 4; ++n) {
      int nn = wc * 64 + n * 16 + frow;
      bfr[n] = *(const bf16x8*)(Bs + nn * 68 + ks * 32 + ksel * 8);
    }
#pragma unroll
    for (int m = 0; m < 4; ++m)
#pragma unroll
      for (int n = 0; n < 4; ++n)
        acc[m][n] = __builtin_amdgcn_mfma_f32_16x16x32_bf16(af[m], bfr[n], acc[m][n], 0, 0, 0);
  }

  const int crow0 = (lane >> 4) * 4;
  const int ccol  = lane & 15;
  float* Cb = DT + (size_t)b * D_INNER * L_SEQ;
#pragma unroll
  for (int m = 0; m < 4; ++m) {
    int gr0 = dm * 128 + wr * 64 + m * 16 + crow0;
#pragma unroll
    for (int n = 0; n < 4; ++n) {
      int gc = ln * 128 + wc * 64 + n * 16 + ccol;
#pragma unroll
      for (int i = 0; i < 4; ++i)
        Cb[(size_t)(gr0 + i) * L_SEQ + gc] = acc[m][n][i];
    }
  }
}

extern "C" void kernel_launch(void* const* d_in, const int* in_sizes, int n_in,
                              void* d_out, int out_size, void* d_ws, size_t ws_size,
                              hipStream_t stream) {
  const float* hs   = (const float*)d_in[0];
  const float* ipw  = (const float*)d_in[1];
  const float* cw   = (const float*)d_in[2];
  const float* cb   = (const float*)d_in[3];
  const float* xpw  = (const float*)d_in[4];
  const float* dpw  = (const float*)d_in[5];
  const float* alog = (const float*)d_in[6];

  float* out    = (float*)d_out;
  float* dt_out = out + OFF_DT;
  float* a_out  = out + OFF_A;
  float* b_out  = out + OFF_B;
  float* c_out  = out + OFF_C;
  float* x_out  = out + OFF_X;

  // Scratch plan:
  //  - bf16 HS (16.8 MB) + bf16 W-half (4.2 MB) in x region of d_out (dead
  //    after k_inproj; k_xproj_fused overwrites x region afterwards).
  //  - xpre (pre-conv x, bf16, 33.5 MB) in dt region (dead after xproj;
  //    k_dt_mfma overwrites).
  //  - d_ws: xdbl fp32 (2 MB) | XWb bf16 (384 KB) | DWb bf16 (256 KB).
  unsigned short* bfHS = (unsigned short*)x_out;
  unsigned short* bfW  = bfHS + (size_t)B_SZ * L_SEQ * D_MODEL;
  unsigned short* xpre = (unsigned short*)dt_out;
  float* xdbl = (float*)d_ws;
  unsigned short* xwb = (unsigned short*)((char*)d_ws + 2097152);
  unsigned short* dwb = (unsigned short*)((char*)d_ws + 2097152 + 393216);

  // One fused prep launch: 4 casts + zero xdbl + zero B|C + A = -exp(A_log).
  k_prep<<<dim3((N4_TOT + 255) / 256), 256, 0, stream>>>(
      (const float4*)hs, (const float4*)ipw, (const float4*)xpw,
      (const float4*)dpw, (const float4*)alog,
      (ushort4*)bfHS, (ushort4*)bfW, (ushort4*)xwb, (ushort4*)dwb,
      (float4*)xdbl, (float4*)b_out, (float4*)a_out);

  k_inproj_mfma<<<dim3(16, 16, 4), 256, 0, stream>>>(bfW, bfHS, xpre);
  k_xproj_fused<<<dim3(16, 8, 4), 256, 0, stream>>>(xwb, xpre, cw, cb,
                                                    x_out, xdbl, b_out, c_out);
  k_dt_mfma<<<dim3(16, 16, 4), 256, 0, stream>>>(dwb, xdbl, dt_out);
}